// Round 1
// baseline (783.380 us; speedup 1.0000x reference)
//
#include <hip/hip_runtime.h>
#include <cstdint>
#include <cstddef>

// ModalityMoE: B=8, L=384, D=1024, E=4, K=2, H=4096
// R4: latency attack. Evidence: gemm2 MfmaUtil 15%, HBM 25%, VALUBusy 8%,
// Occupancy 15.6% -> latency-bound, not roofline. Single-buffered K-loop
// (barrier/stage/barrier+vmcnt0/compute) exposes full L2/L3-miss latency per
// 64-K step, and gemm2's 1-3 maybe-skipped slots per block create a straggler
// tail. Fix: (1) 2-phase double-buffered LDS pipeline (stage k+1 issued right
// after the barrier, compute k from the other 32KB phase; ONE barrier/step);
// (2) gemm2 work flattened over (slot,kstep) and split evenly across the 4 kc
// blocks (32-48 uniform steps/block). LDS 34816->65536 (2 blocks/CU).

#define DEV __device__ __forceinline__

typedef __attribute__((ext_vector_type(8))) __bf16 bf16x8;
typedef __attribute__((ext_vector_type(4))) __bf16 bf16x4;
typedef __attribute__((ext_vector_type(4))) float f32x4;

static constexpr int Bb = 8, Ll = 384, Dd = 1024, Ee = 4, Hh = 4096;

DEV void load_lds16(const void* g, void* l) {
  __builtin_amdgcn_global_load_lds(
      (const __attribute__((address_space(1))) void*)g,
      (__attribute__((address_space(3))) void*)l, 16, 0, 0);
}

DEV float gelu_tanh(float x) {
  float u = 0.7978845608028654f * (x + 0.044715f * x * x * x);
  float t = 1.0f - 2.0f / (1.0f + __expf(2.0f * u));
  return 0.5f * x * (1.0f + t);
}

DEV float wave_red(float v) {
#pragma unroll
  for (int o = 32; o > 0; o >>= 1) v += __shfl_down(v, o, 64);
  return v;
}

// ---------------- conversion / transpose ----------------

__global__ void cvt_x_kernel(const float* __restrict__ src, __bf16* __restrict__ dst, int n4) {
  int i = blockIdx.x * blockDim.x + threadIdx.x;
  if (i >= n4) return;
  float4 v = ((const float4*)src)[i];
  bf16x4 o;
  o.x = (__bf16)v.x; o.y = (__bf16)v.y; o.z = (__bf16)v.z; o.w = (__bf16)v.w;
  ((bf16x4*)dst)[i] = o;
}

// src: [bz][nr][nc] fp32 -> dst: [bz][nc][nr] bf16
__global__ void transpose_cvt_kernel(const float* __restrict__ src, __bf16* __restrict__ dst,
                                     int nr, int nc) {
  __shared__ float t[32][33];
  size_t base = (size_t)blockIdx.z * nr * nc;
  src += base; dst += base;
  int x = threadIdx.x & 31, y = threadIdx.x >> 5;
  int c0 = blockIdx.x * 32, r0 = blockIdx.y * 32;
#pragma unroll
  for (int r = 0; r < 4; ++r) {
    int rr = y + r * 8;
    t[rr][x] = src[(size_t)(r0 + rr) * nc + c0 + x];
  }
  __syncthreads();
#pragma unroll
  for (int r = 0; r < 4; ++r) {
    int rr = y + r * 8;
    dst[(size_t)(c0 + rr) * nr + r0 + x] = (__bf16)t[x][rr];
  }
}

// ---------------- gating ----------------

__global__ void agg_kernel(const float* __restrict__ ctx, float* __restrict__ part) {
  int c = blockIdx.x, b = blockIdx.y, t = threadIdx.x;
  int d0 = t * 4;
  float4 sum = {0.f, 0.f, 0.f, 0.f};
  const float* p = ctx + ((size_t)(b * Ll + c * 64)) * Dd + d0;
  for (int l = 0; l < 64; ++l) {
    float4 v = *(const float4*)(p + (size_t)l * Dd);
    sum.x += v.x; sum.y += v.y; sum.z += v.z; sum.w += v.w;
  }
  *(float4*)(part + ((size_t)(b * 6 + c)) * Dd + d0) = sum;
}

__global__ void gate_kernel(const float* __restrict__ part, const float* __restrict__ tc,
                            const float* __restrict__ gW, const float* __restrict__ gb,
                            const float* __restrict__ tW, const float* __restrict__ tb,
                            int* __restrict__ slotE, float* __restrict__ slotW) {
  __shared__ float gi[3 * Dd];
  __shared__ float st[Dd];
  __shared__ float red[12];
  int b = blockIdx.x, t = threadIdx.x;
  const float* pb = part + (size_t)b * 6 * Dd;
#pragma unroll
  for (int k = 0; k < 4; ++k) {
    int d = t * 4 + k;
    float p0 = pb[d], p1 = pb[Dd + d], p2 = pb[2 * Dd + d];
    float p3 = pb[3 * Dd + d], p4 = pb[4 * Dd + d], p5 = pb[5 * Dd + d];
    gi[d]          = (p0 + p1 + p2 + p3 + p4 + p5) * (1.0f / 384.0f);
    gi[Dd + d]     = (p0 + p1 + p4 + p5) * (1.0f / 256.0f);
    gi[2 * Dd + d] = (p2 + p3 + p4 + p5) * (1.0f / 256.0f);
    float tv = tc[b * Dd + d];
    st[d] = tv / (1.0f + __expf(-tv));
  }
  __syncthreads();
  int wid = t >> 6, lane = t & 63;
  float aL = 0.f;
  for (int i = lane; i < 3 * Dd; i += 64) aL += gi[i] * gW[wid * 3 * Dd + i];
  aL = wave_red(aL);
  float aA = 0.f, aB = 0.f;
  for (int i = lane; i < Dd; i += 64) {
    float s = st[i];
    aA += s * tW[wid * Dd + i];
    aB += s * tW[(wid + 4) * Dd + i];
  }
  aA = wave_red(aA); aB = wave_red(aB);
  if (lane == 0) { red[wid] = aL; red[4 + wid] = aA; red[8 + wid] = aB; }
  __syncthreads();
  if (t == 0) {
    float lg[4];
#pragma unroll
    for (int e = 0; e < 4; ++e) {
      float logit = red[e] + gb[e];
      float scale = red[4 + e] + tb[e];
      float shift = red[8 + e] + tb[4 + e];
      lg[e] = logit * (1.0f + scale) + shift;
    }
    float m = fmaxf(fmaxf(lg[0], lg[1]), fmaxf(lg[2], lg[3]));
    float p[4], sum = 0.f;
#pragma unroll
    for (int e = 0; e < 4; ++e) { p[e] = __expf(lg[e] - m); sum += p[e]; }
#pragma unroll
    for (int e = 0; e < 4; ++e) p[e] /= sum;
    int i0 = 0;
    for (int e = 1; e < 4; ++e) if (p[e] > p[i0]) i0 = e;
    int i1 = -1;
    for (int e = 0; e < 4; ++e) if (e != i0 && (i1 < 0 || p[e] > p[i1])) i1 = e;
    float sw = p[i0] + p[i1] + 1e-8f;
    slotE[b * 4 + 0] = i0; slotE[b * 4 + 1] = i1;
    slotW[b * 4 + 0] = p[i0] / sw; slotW[b * 4 + 1] = p[i1] / sw;
  }
}

// ---- GEMM1: H = w * gelu(X @ W1 + b1), bf16 out; 2-phase dbuf pipeline ----

__global__ __launch_bounds__(256) void gemm1_kernel(
    const __bf16* __restrict__ Xbf, const __bf16* __restrict__ W1T,
    const __bf16* __restrict__ S1T, const float* __restrict__ eb1,
    const float* __restrict__ sb1, const int* __restrict__ slotE,
    const float* __restrict__ slotW, __bf16* __restrict__ Hbuf, int bbase) {
  constexpr int K = Dd;  // 1024
  int nt = blockIdx.x, mt = blockIdx.y, z = blockIdx.z;
  int bl = z / 3, s = z - bl * 3;
  int b = bbase + bl;
  int e = (s == 2) ? Ee : slotE[b * 4 + s];
  if ((e == 1 && mt == 1) || (e == 2 && mt == 0)) return;  // mask-aligned skip
  float wgt = (s == 2) ? 1.0f : slotW[b * 4 + s];

  const __bf16* Ab = Xbf + ((size_t)(b * Ll + mt * 128)) * K;
  const __bf16* Bbp = (e < Ee ? W1T + (size_t)e * Hh * K : S1T) + (size_t)(nt * 128) * K;
  const float* b1p = (e < Ee ? eb1 + e * Hh : sb1);

  __shared__ __align__(16) char smem[65536];  // 2 phases x (16KB A + 16KB B)

  int tid = threadIdx.x, wid = tid >> 6, lane = tid & 63;
  int q = lane >> 4, l16 = lane & 15;
  int wm = wid >> 1, wn = wid & 1;

  const __bf16* gp[8];
  uint32_t lo[8];
#pragma unroll
  for (int u = 0; u < 8; ++u) {
    int c = wid * 8 + u;
    int isB = c >> 4;
    int blk = (c & 15) >> 1;
    int ks = c & 1;
    const __bf16* base = isB ? Bbp : Ab;
    gp[u] = base + (size_t)(blk * 16 + l16) * K + ks * 32 + q * 8;
    lo[u] = (uint32_t)(isB * 16384 + (blk * 2 + ks) * 1024);
  }

  f32x4 acc[4][4];
  f32x4 zero = {0.f, 0.f, 0.f, 0.f};
#pragma unroll
  for (int i = 0; i < 4; ++i)
#pragma unroll
    for (int j = 0; j < 4; ++j) acc[i][j] = zero;

  // prologue: stage kt=0 into phase 0
#pragma unroll
  for (int u = 0; u < 8; ++u) load_lds16(gp[u], smem + lo[u]);

  constexpr int NK = K / 64;  // 16
  for (int kt = 0; kt < NK; ++kt) {
    int ph = kt & 1;
    __syncthreads();  // drains vmcnt(0): phase ph staging (issued last iter) done
    if (kt + 1 < NK) {
#pragma unroll
      for (int u = 0; u < 8; ++u) {
        gp[u] += 64;
        load_lds16(gp[u], smem + lo[u] + (ph ^ 1) * 32768);
      }
    }
    const char* sm = (const char*)smem + ph * 32768;
#pragma unroll
    for (int ks = 0; ks < 2; ++ks) {
      bf16x8 a[4], bb[4];
#pragma unroll
      for (int i = 0; i < 4; ++i)
        a[i] = *(const bf16x8*)(sm + (((wm * 4 + i) * 2 + ks) * 64 + lane) * 16);
#pragma unroll
      for (int j = 0; j < 4; ++j)
        bb[j] = *(const bf16x8*)(sm + 16384 + (((wn * 4 + j) * 2 + ks) * 64 + lane) * 16);
#pragma unroll
      for (int i = 0; i < 4; ++i)
#pragma unroll
        for (int j = 0; j < 4; ++j)
          acc[i][j] = __builtin_amdgcn_mfma_f32_16x16x32_bf16(a[i], bb[j], acc[i][j], 0, 0, 0);
    }
  }

  float bias[4];
#pragma unroll
  for (int j = 0; j < 4; ++j) bias[j] = b1p[nt * 128 + wn * 64 + j * 16 + l16];

  __syncthreads();
  __bf16* tile = (__bf16*)smem;  // [128][136]
#pragma unroll
  for (int i = 0; i < 4; ++i)
#pragma unroll
    for (int j = 0; j < 4; ++j)
#pragma unroll
      for (int r = 0; r < 4; ++r) {
        float x = acc[i][j][r] + bias[j];
        int row = wm * 64 + i * 16 + q * 4 + r;
        int col = wn * 64 + j * 16 + l16;
        tile[row * 136 + col] = (__bf16)(wgt * gelu_tanh(x));
      }
  __syncthreads();
  __bf16* Hrow = Hbuf + ((size_t)(bl * 3 + s) * Ll + mt * 128) * Hh + nt * 128;
#pragma unroll
  for (int t2 = 0; t2 < 8; ++t2) {
    int gidx = t2 * 256 + tid;
    int row = gidx >> 4, cg = gidx & 15;
    bf16x8 v = *(const bf16x8*)(tile + row * 136 + cg * 8);
    *(bf16x8*)(Hrow + (size_t)row * Hh + cg * 8) = v;
  }
}

// ---- GEMM2: flattened (slot,kstep) space split evenly over 4 kc blocks; ----
// ---- 2-phase dbuf pipeline runs straight across slot boundaries.        ----

__global__ __launch_bounds__(256) void gemm2_kernel(
    const __bf16* __restrict__ Hbuf, const __bf16* __restrict__ W2T,
    const __bf16* __restrict__ S2T, const float* __restrict__ eb2,
    const float* __restrict__ sb2, const int* __restrict__ slotE,
    const float* __restrict__ slotW, float* __restrict__ out,
    __bf16* __restrict__ pbuf, int bbase, int bc) {
  constexpr int K = Hh;  // 4096 -> 64 steps of BK=64 per slot
  int nt = blockIdx.x, mt = blockIdx.y, z = blockIdx.z;
  int kc = z & 3, bl = z >> 2;
  int b = bbase + bl;

  __shared__ __align__(16) char smem[65536];

  int tid = threadIdx.x, wid = tid >> 6, lane = tid & 63;
  int q = lane >> 4, l16 = lane & 15;
  int wm = wid >> 1, wn = wid & 1;

  // ---- build compacted active-slot list in NAMED registers (no scratch) ----
  const __bf16 *A0 = nullptr, *A1 = nullptr, *A2 = nullptr;
  const __bf16 *B0 = nullptr, *B1 = nullptr, *B2 = nullptr;
  float biasacc[4] = {0.f, 0.f, 0.f, 0.f};
  int nact = 0;
#pragma unroll
  for (int s = 0; s < 3; ++s) {
    int e = (s == 2) ? Ee : slotE[b * 4 + s];
    bool skip = (e == 1 && mt == 1) || (e == 2 && mt == 0);
    if (!skip) {
      const __bf16* Ap = Hbuf + ((size_t)(bl * 3 + s) * Ll + mt * 128) * K;
      const __bf16* Bp = (e < Ee ? W2T + (size_t)e * Dd * K : S2T) + (size_t)(nt * 128) * K;
      if (nact == 0)      { A0 = Ap; B0 = Bp; }
      else if (nact == 1) { A1 = Ap; B1 = Bp; }
      else                { A2 = Ap; B2 = Bp; }
      if (kc == 0) {  // bias ownership: kc 0 adds all active-slot biases
        float wgt = (s == 2) ? 1.0f : slotW[b * 4 + s];
        const float* b2p = (e < Ee ? eb2 + e * Dd : sb2);
#pragma unroll
        for (int j = 0; j < 4; ++j)
          biasacc[j] += wgt * b2p[nt * 128 + wn * 64 + j * 16 + l16];
      }
      ++nact;
    }
  }

  // nact in {2,3}: total flat steps = nact*64, divisible by 4 -> uniform split
  int quarter = (nact * 64) >> 2;  // 32 or 48
  int f0 = kc * quarter, f1 = f0 + quarter;

  uint32_t lo[8];
#pragma unroll
  for (int u = 0; u < 8; ++u) {
    int c = wid * 8 + u;
    int isB = c >> 4;
    int blk = (c & 15) >> 1;
    int ks = c & 1;
    lo[u] = (uint32_t)(isB * 16384 + (blk * 2 + ks) * 1024);
  }

  const __bf16* gp[8];
  auto setupPtrs = [&](int ft) {
    int sl = ft >> 6, kt = ft & 63;
    const __bf16* Ap = (sl == 0) ? A0 : ((sl == 1) ? A1 : A2);
    const __bf16* Bp = (sl == 0) ? B0 : ((sl == 1) ? B1 : B2);
#pragma unroll
    for (int u = 0; u < 8; ++u) {
      int c = wid * 8 + u;
      int isB = c >> 4;
      int blk = (c & 15) >> 1;
      int ks = c & 1;
      const __bf16* base = isB ? Bp : Ap;
      gp[u] = base + (size_t)(blk * 16 + l16) * K + ks * 32 + q * 8 + (size_t)kt * 64;
    }
  };

  f32x4 acc[4][4];
  f32x4 zero = {0.f, 0.f, 0.f, 0.f};
#pragma unroll
  for (int i = 0; i < 4; ++i)
#pragma unroll
    for (int j = 0; j < 4; ++j) acc[i][j] = zero;

  // prologue: stage step f0 into phase 0
  setupPtrs(f0);
#pragma unroll
  for (int u = 0; u < 8; ++u) load_lds16(gp[u], smem + lo[u]);

  for (int ft = f0; ft < f1; ++ft) {
    int ph = (ft - f0) & 1;
    __syncthreads();  // drains vmcnt(0): phase ph staging done (had full compute to land)
    if (ft + 1 < f1) {
      if (((ft + 1) & 63) == 0) {
        setupPtrs(ft + 1);  // slot boundary: rebuild pointers
      } else {
#pragma unroll
        for (int u = 0; u < 8; ++u) gp[u] += 64;
      }
#pragma unroll
      for (int u = 0; u < 8; ++u) load_lds16(gp[u], smem + lo[u] + (ph ^ 1) * 32768);
    }
    const char* sm = (const char*)smem + ph * 32768;
#pragma unroll
    for (int ks = 0; ks < 2; ++ks) {
      bf16x8 a[4], bb[4];
#pragma unroll
      for (int i = 0; i < 4; ++i)
        a[i] = *(const bf16x8*)(sm + (((wm * 4 + i) * 2 + ks) * 64 + lane) * 16);
#pragma unroll
      for (int j = 0; j < 4; ++j)
        bb[j] = *(const bf16x8*)(sm + 16384 + (((wn * 4 + j) * 2 + ks) * 64 + lane) * 16);
#pragma unroll
      for (int i = 0; i < 4; ++i)
#pragma unroll
        for (int j = 0; j < 4; ++j)
          acc[i][j] = __builtin_amdgcn_mfma_f32_16x16x32_bf16(a[i], bb[j], acc[i][j], 0, 0, 0);
    }
  }

  if (pbuf) {
    // non-atomic bf16 partial store via LDS repack (coalesced bf16x8)
    __syncthreads();
    __bf16* tile = (__bf16*)smem;  // [128][136]
#pragma unroll
    for (int i = 0; i < 4; ++i)
#pragma unroll
      for (int j = 0; j < 4; ++j)
#pragma unroll
        for (int r = 0; r < 4; ++r) {
          int row = wm * 64 + i * 16 + q * 4 + r;
          int col = wn * 64 + j * 16 + l16;
          tile[row * 136 + col] = (__bf16)(acc[i][j][r] + biasacc[j]);
        }
    __syncthreads();
    __bf16* Prow = pbuf + (((size_t)(kc * bc + bl) * Ll + mt * 128)) * Dd + nt * 128;
#pragma unroll
    for (int t2 = 0; t2 < 8; ++t2) {
      int gidx = t2 * 256 + tid;
      int row = gidx >> 4, cg = gidx & 15;
      bf16x8 v = *(const bf16x8*)(tile + row * 136 + cg * 8);
      *(bf16x8*)(Prow + (size_t)row * Dd + cg * 8) = v;
    }
  } else {
    float* orow = out + ((size_t)(b * Ll + mt * 128)) * Dd + nt * 128;
#pragma unroll
    for (int i = 0; i < 4; ++i)
#pragma unroll
      for (int j = 0; j < 4; ++j)
#pragma unroll
        for (int r = 0; r < 4; ++r) {
          int row = wm * 64 + i * 16 + q * 4 + r;
          int col = wn * 64 + j * 16 + l16;
          atomicAdd(orow + (size_t)row * Dd + col, acc[i][j][r] + biasacc[j]);
        }
  }
}

// reduce: out[i] = sum_{kc<4} pbuf[kc][i]  (8 elems/thread)
__global__ void reduce4_kernel(const __bf16* __restrict__ pbuf, float* __restrict__ out,
                               int n8, size_t stride) {
  int i = blockIdx.x * blockDim.x + threadIdx.x;
  if (i >= n8) return;
  size_t base = (size_t)i * 8;
  float sum[8];
#pragma unroll
  for (int k = 0; k < 8; ++k) sum[k] = 0.f;
#pragma unroll
  for (int kc = 0; kc < 4; ++kc) {
    bf16x8 v = *(const bf16x8*)(pbuf + kc * stride + base);
#pragma unroll
    for (int k = 0; k < 8; ++k) sum[k] += (float)v[k];
  }
  float4 o0 = {sum[0], sum[1], sum[2], sum[3]};
  float4 o1 = {sum[4], sum[5], sum[6], sum[7]};
  *(float4*)(out + base) = o0;
  *(float4*)(out + base + 4) = o1;
}

// ---------------- host ----------------

extern "C" void kernel_launch(void* const* d_in, const int* in_sizes, int n_in,
                              void* d_out, int out_size, void* d_ws, size_t ws_size,
                              hipStream_t stream) {
  (void)in_sizes; (void)n_in;
  const float* ctx = (const float*)d_in[0];
  const float* tc  = (const float*)d_in[1];
  const float* gW  = (const float*)d_in[2];
  const float* gb  = (const float*)d_in[3];
  const float* tW  = (const float*)d_in[4];
  const float* tb  = (const float*)d_in[5];
  const float* eW1 = (const float*)d_in[6];
  const float* eb1 = (const float*)d_in[7];
  const float* eW2 = (const float*)d_in[8];
  const float* eb2 = (const float*)d_in[9];
  const float* sW1 = (const float*)d_in[10];
  const float* sb1 = (const float*)d_in[11];
  const float* sW2 = (const float*)d_in[12];
  const float* sb2 = (const float*)d_in[13];
  float* out = (float*)d_out;

  char* ws = (char*)d_ws;
  size_t off = 0;
  auto alloc = [&](size_t sz) { size_t o = off; off += (sz + 255) & ~(size_t)255; return o; };
  size_t oW1T = alloc((size_t)Ee * Hh * Dd * 2);
  size_t oW2T = alloc((size_t)Ee * Dd * Hh * 2);
  size_t oS1T = alloc((size_t)Hh * Dd * 2);
  size_t oS2T = alloc((size_t)Dd * Hh * 2);
  size_t oX   = alloc((size_t)Bb * Ll * Dd * 2);
  size_t oP   = alloc((size_t)Bb * 6 * Dd * 4);
  size_t oSE  = alloc(Bb * 4 * sizeof(int));
  size_t oSW  = alloc(Bb * 4 * sizeof(float));
  size_t fixed = off;

  // plan selection: bc = batches/chunk, use_pbuf = non-atomic partials
  auto hbufB = [&](int bc) { return (size_t)bc * 3 * Ll * Hh * 2; };
  auto pbufB = [&](int bc) { return (size_t)4 * bc * Ll * Dd * 2; };
  int bc = 1; bool use_pbuf = false;
  if (fixed + hbufB(8) + pbufB(8) + 512 <= ws_size)      { bc = 8; use_pbuf = true; }
  else if (fixed + hbufB(4) + pbufB(4) + 512 <= ws_size) { bc = 4; use_pbuf = true; }
  else if (fixed + hbufB(4) + 512 <= ws_size)            { bc = 4; use_pbuf = false; }
  else if (fixed + hbufB(2) + 512 <= ws_size)            { bc = 2; use_pbuf = false; }
  else                                                   { bc = 1; use_pbuf = false; }
  int nchunk = Bb / bc;
  size_t oH = alloc(hbufB(bc));
  size_t oPB = use_pbuf ? alloc(pbufB(bc)) : 0;

  __bf16* W1T = (__bf16*)(ws + oW1T);
  __bf16* W2T = (__bf16*)(ws + oW2T);
  __bf16* S1T = (__bf16*)(ws + oS1T);
  __bf16* S2T = (__bf16*)(ws + oS2T);
  __bf16* Xbf = (__bf16*)(ws + oX);
  float*  part = (float*)(ws + oP);
  int*    slotE = (int*)(ws + oSE);
  float*  slotW = (float*)(ws + oSW);
  __bf16* Hbuf = (__bf16*)(ws + oH);
  __bf16* Pbuf = use_pbuf ? (__bf16*)(ws + oPB) : nullptr;

  // pbuf path fully overwrites out via reduce4 -> memset only needed for atomics
  if (!use_pbuf)
    hipMemsetAsync(d_out, 0, (size_t)out_size * sizeof(float), stream);

  cvt_x_kernel<<<(Bb * Ll * Dd / 4 + 255) / 256, 256, 0, stream>>>(ctx, Xbf, Bb * Ll * Dd / 4);
  transpose_cvt_kernel<<<dim3(Hh / 32, Dd / 32, Ee), 256, 0, stream>>>(eW1, W1T, Dd, Hh);
  transpose_cvt_kernel<<<dim3(Dd / 32, Hh / 32, Ee), 256, 0, stream>>>(eW2, W2T, Hh, Dd);
  transpose_cvt_kernel<<<dim3(Hh / 32, Dd / 32, 1), 256, 0, stream>>>(sW1, S1T, Dd, Hh);
  transpose_cvt_kernel<<<dim3(Dd / 32, Hh / 32, 1), 256, 0, stream>>>(sW2, S2T, Hh, Dd);
  agg_kernel<<<dim3(6, Bb), 256, 0, stream>>>(ctx, part);
  gate_kernel<<<Bb, 256, 0, stream>>>(part, tc, gW, gb, tW, tb, slotE, slotW);

  for (int c = 0; c < nchunk; ++c) {
    gemm1_kernel<<<dim3(Hh / 128, 3, bc * 3), 256, 0, stream>>>(
        Xbf, W1T, S1T, eb1, sb1, slotE, slotW, Hbuf, c * bc);
    gemm2_kernel<<<dim3(Dd / 128, 3, bc * 4), 256, 0, stream>>>(
        Hbuf, W2T, S2T, eb2, sb2, slotE, slotW, out, Pbuf, c * bc, bc);
    if (use_pbuf) {
      int n8 = bc * Ll * Dd / 8;
      reduce4_kernel<<<(n8 + 255) / 256, 256, 0, stream>>>(
          Pbuf, out + (size_t)c * bc * Ll * Dd, n8, (size_t)bc * Ll * Dd);
    }
  }
}

// Round 2
// 581.293 us; speedup vs baseline: 1.3476x; 1.3476x over previous
//
#include <hip/hip_runtime.h>
#include <cstdint>
#include <cstddef>

// ModalityMoE: B=8, L=384, D=1024, E=4, K=2, H=4096
// R5: revert gemm2 flattening (R4 regression: WRITE_SIZE 24->290MB = scratch
// spill from lambda/runtime-indexed pointer re-setup; dur 185->384us). Keep
// the 2-phase dbuf pipeline (proven safe+mildly positive on gemm1) but in the
// R3 per-slot static structure: gp[] built once per slot with constant
// indices, prologue stage into phase 0, 16-step loop with ONE barrier/step
// and next-step stage issued immediately after the barrier.
// Predicted: gemm2 WRITE ~25MB, dur 150-185us, MfmaUtil 15-20%, e2e ~560-600.

#define DEV __device__ __forceinline__

typedef __attribute__((ext_vector_type(8))) __bf16 bf16x8;
typedef __attribute__((ext_vector_type(4))) __bf16 bf16x4;
typedef __attribute__((ext_vector_type(4))) float f32x4;

static constexpr int Bb = 8, Ll = 384, Dd = 1024, Ee = 4, Hh = 4096;

DEV void load_lds16(const void* g, void* l) {
  __builtin_amdgcn_global_load_lds(
      (const __attribute__((address_space(1))) void*)g,
      (__attribute__((address_space(3))) void*)l, 16, 0, 0);
}

DEV float gelu_tanh(float x) {
  float u = 0.7978845608028654f * (x + 0.044715f * x * x * x);
  float t = 1.0f - 2.0f / (1.0f + __expf(2.0f * u));
  return 0.5f * x * (1.0f + t);
}

DEV float wave_red(float v) {
#pragma unroll
  for (int o = 32; o > 0; o >>= 1) v += __shfl_down(v, o, 64);
  return v;
}

// ---------------- conversion / transpose ----------------

__global__ void cvt_x_kernel(const float* __restrict__ src, __bf16* __restrict__ dst, int n4) {
  int i = blockIdx.x * blockDim.x + threadIdx.x;
  if (i >= n4) return;
  float4 v = ((const float4*)src)[i];
  bf16x4 o;
  o.x = (__bf16)v.x; o.y = (__bf16)v.y; o.z = (__bf16)v.z; o.w = (__bf16)v.w;
  ((bf16x4*)dst)[i] = o;
}

// src: [bz][nr][nc] fp32 -> dst: [bz][nc][nr] bf16
__global__ void transpose_cvt_kernel(const float* __restrict__ src, __bf16* __restrict__ dst,
                                     int nr, int nc) {
  __shared__ float t[32][33];
  size_t base = (size_t)blockIdx.z * nr * nc;
  src += base; dst += base;
  int x = threadIdx.x & 31, y = threadIdx.x >> 5;
  int c0 = blockIdx.x * 32, r0 = blockIdx.y * 32;
#pragma unroll
  for (int r = 0; r < 4; ++r) {
    int rr = y + r * 8;
    t[rr][x] = src[(size_t)(r0 + rr) * nc + c0 + x];
  }
  __syncthreads();
#pragma unroll
  for (int r = 0; r < 4; ++r) {
    int rr = y + r * 8;
    dst[(size_t)(c0 + rr) * nr + r0 + x] = (__bf16)t[x][rr];
  }
}

// ---------------- gating ----------------

__global__ void agg_kernel(const float* __restrict__ ctx, float* __restrict__ part) {
  int c = blockIdx.x, b = blockIdx.y, t = threadIdx.x;
  int d0 = t * 4;
  float4 sum = {0.f, 0.f, 0.f, 0.f};
  const float* p = ctx + ((size_t)(b * Ll + c * 64)) * Dd + d0;
  for (int l = 0; l < 64; ++l) {
    float4 v = *(const float4*)(p + (size_t)l * Dd);
    sum.x += v.x; sum.y += v.y; sum.z += v.z; sum.w += v.w;
  }
  *(float4*)(part + ((size_t)(b * 6 + c)) * Dd + d0) = sum;
}

__global__ void gate_kernel(const float* __restrict__ part, const float* __restrict__ tc,
                            const float* __restrict__ gW, const float* __restrict__ gb,
                            const float* __restrict__ tW, const float* __restrict__ tb,
                            int* __restrict__ slotE, float* __restrict__ slotW) {
  __shared__ float gi[3 * Dd];
  __shared__ float st[Dd];
  __shared__ float red[12];
  int b = blockIdx.x, t = threadIdx.x;
  const float* pb = part + (size_t)b * 6 * Dd;
#pragma unroll
  for (int k = 0; k < 4; ++k) {
    int d = t * 4 + k;
    float p0 = pb[d], p1 = pb[Dd + d], p2 = pb[2 * Dd + d];
    float p3 = pb[3 * Dd + d], p4 = pb[4 * Dd + d], p5 = pb[5 * Dd + d];
    gi[d]          = (p0 + p1 + p2 + p3 + p4 + p5) * (1.0f / 384.0f);
    gi[Dd + d]     = (p0 + p1 + p4 + p5) * (1.0f / 256.0f);
    gi[2 * Dd + d] = (p2 + p3 + p4 + p5) * (1.0f / 256.0f);
    float tv = tc[b * Dd + d];
    st[d] = tv / (1.0f + __expf(-tv));
  }
  __syncthreads();
  int wid = t >> 6, lane = t & 63;
  float aL = 0.f;
  for (int i = lane; i < 3 * Dd; i += 64) aL += gi[i] * gW[wid * 3 * Dd + i];
  aL = wave_red(aL);
  float aA = 0.f, aB = 0.f;
  for (int i = lane; i < Dd; i += 64) {
    float s = st[i];
    aA += s * tW[wid * Dd + i];
    aB += s * tW[(wid + 4) * Dd + i];
  }
  aA = wave_red(aA); aB = wave_red(aB);
  if (lane == 0) { red[wid] = aL; red[4 + wid] = aA; red[8 + wid] = aB; }
  __syncthreads();
  if (t == 0) {
    float lg[4];
#pragma unroll
    for (int e = 0; e < 4; ++e) {
      float logit = red[e] + gb[e];
      float scale = red[4 + e] + tb[e];
      float shift = red[8 + e] + tb[4 + e];
      lg[e] = logit * (1.0f + scale) + shift;
    }
    float m = fmaxf(fmaxf(lg[0], lg[1]), fmaxf(lg[2], lg[3]));
    float p[4], sum = 0.f;
#pragma unroll
    for (int e = 0; e < 4; ++e) { p[e] = __expf(lg[e] - m); sum += p[e]; }
#pragma unroll
    for (int e = 0; e < 4; ++e) p[e] /= sum;
    int i0 = 0;
    for (int e = 1; e < 4; ++e) if (p[e] > p[i0]) i0 = e;
    int i1 = -1;
    for (int e = 0; e < 4; ++e) if (e != i0 && (i1 < 0 || p[e] > p[i1])) i1 = e;
    float sw = p[i0] + p[i1] + 1e-8f;
    slotE[b * 4 + 0] = i0; slotE[b * 4 + 1] = i1;
    slotW[b * 4 + 0] = p[i0] / sw; slotW[b * 4 + 1] = p[i1] / sw;
  }
}

// ---- GEMM1: H = w * gelu(X @ W1 + b1), bf16 out; 2-phase dbuf pipeline ----

__global__ __launch_bounds__(256) void gemm1_kernel(
    const __bf16* __restrict__ Xbf, const __bf16* __restrict__ W1T,
    const __bf16* __restrict__ S1T, const float* __restrict__ eb1,
    const float* __restrict__ sb1, const int* __restrict__ slotE,
    const float* __restrict__ slotW, __bf16* __restrict__ Hbuf, int bbase) {
  constexpr int K = Dd;  // 1024
  int nt = blockIdx.x, mt = blockIdx.y, z = blockIdx.z;
  int bl = z / 3, s = z - bl * 3;
  int b = bbase + bl;
  int e = (s == 2) ? Ee : slotE[b * 4 + s];
  if ((e == 1 && mt == 1) || (e == 2 && mt == 0)) return;  // mask-aligned skip
  float wgt = (s == 2) ? 1.0f : slotW[b * 4 + s];

  const __bf16* Ab = Xbf + ((size_t)(b * Ll + mt * 128)) * K;
  const __bf16* Bbp = (e < Ee ? W1T + (size_t)e * Hh * K : S1T) + (size_t)(nt * 128) * K;
  const float* b1p = (e < Ee ? eb1 + e * Hh : sb1);

  __shared__ __align__(16) char smem[65536];  // 2 phases x (16KB A + 16KB B)

  int tid = threadIdx.x, wid = tid >> 6, lane = tid & 63;
  int q = lane >> 4, l16 = lane & 15;
  int wm = wid >> 1, wn = wid & 1;

  const __bf16* gp[8];
  uint32_t lo[8];
#pragma unroll
  for (int u = 0; u < 8; ++u) {
    int c = wid * 8 + u;
    int isB = c >> 4;
    int blk = (c & 15) >> 1;
    int ks = c & 1;
    const __bf16* base = isB ? Bbp : Ab;
    gp[u] = base + (size_t)(blk * 16 + l16) * K + ks * 32 + q * 8;
    lo[u] = (uint32_t)(isB * 16384 + (blk * 2 + ks) * 1024);
  }

  f32x4 acc[4][4];
  f32x4 zero = {0.f, 0.f, 0.f, 0.f};
#pragma unroll
  for (int i = 0; i < 4; ++i)
#pragma unroll
    for (int j = 0; j < 4; ++j) acc[i][j] = zero;

  // prologue: stage kt=0 into phase 0
#pragma unroll
  for (int u = 0; u < 8; ++u) load_lds16(gp[u], smem + lo[u]);

  constexpr int NK = K / 64;  // 16
  for (int kt = 0; kt < NK; ++kt) {
    int ph = kt & 1;
    __syncthreads();  // drains vmcnt(0): phase ph staging (issued last iter) done
    if (kt + 1 < NK) {
#pragma unroll
      for (int u = 0; u < 8; ++u) {
        gp[u] += 64;
        load_lds16(gp[u], smem + lo[u] + (ph ^ 1) * 32768);
      }
    }
    const char* sm = (const char*)smem + ph * 32768;
#pragma unroll
    for (int ks = 0; ks < 2; ++ks) {
      bf16x8 a[4], bb[4];
#pragma unroll
      for (int i = 0; i < 4; ++i)
        a[i] = *(const bf16x8*)(sm + (((wm * 4 + i) * 2 + ks) * 64 + lane) * 16);
#pragma unroll
      for (int j = 0; j < 4; ++j)
        bb[j] = *(const bf16x8*)(sm + 16384 + (((wn * 4 + j) * 2 + ks) * 64 + lane) * 16);
#pragma unroll
      for (int i = 0; i < 4; ++i)
#pragma unroll
        for (int j = 0; j < 4; ++j)
          acc[i][j] = __builtin_amdgcn_mfma_f32_16x16x32_bf16(a[i], bb[j], acc[i][j], 0, 0, 0);
    }
  }

  float bias[4];
#pragma unroll
  for (int j = 0; j < 4; ++j) bias[j] = b1p[nt * 128 + wn * 64 + j * 16 + l16];

  __syncthreads();
  __bf16* tile = (__bf16*)smem;  // [128][136]
#pragma unroll
  for (int i = 0; i < 4; ++i)
#pragma unroll
    for (int j = 0; j < 4; ++j)
#pragma unroll
      for (int r = 0; r < 4; ++r) {
        float x = acc[i][j][r] + bias[j];
        int row = wm * 64 + i * 16 + q * 4 + r;
        int col = wn * 64 + j * 16 + l16;
        tile[row * 136 + col] = (__bf16)(wgt * gelu_tanh(x));
      }
  __syncthreads();
  __bf16* Hrow = Hbuf + ((size_t)(bl * 3 + s) * Ll + mt * 128) * Hh + nt * 128;
#pragma unroll
  for (int t2 = 0; t2 < 8; ++t2) {
    int gidx = t2 * 256 + tid;
    int row = gidx >> 4, cg = gidx & 15;
    bf16x8 v = *(const bf16x8*)(tile + row * 136 + cg * 8);
    *(bf16x8*)(Hrow + (size_t)row * Hh + cg * 8) = v;
  }
}

// ---- GEMM2: R3 per-slot structure + static 2-phase dbuf per slot K-loop ----

__global__ __launch_bounds__(256) void gemm2_kernel(
    const __bf16* __restrict__ Hbuf, const __bf16* __restrict__ W2T,
    const __bf16* __restrict__ S2T, const float* __restrict__ eb2,
    const float* __restrict__ sb2, const int* __restrict__ slotE,
    const float* __restrict__ slotW, float* __restrict__ out,
    __bf16* __restrict__ pbuf, int bbase, int bc) {
  constexpr int K = Hh;     // 4096 total
  constexpr int KC = 1024;  // per-block K chunk
  int nt = blockIdx.x, mt = blockIdx.y, z = blockIdx.z;
  int kc = z & 3, bl = z >> 2;
  int b = bbase + bl;

  __shared__ __align__(16) char smem[65536];

  int tid = threadIdx.x, wid = tid >> 6, lane = tid & 63;
  int q = lane >> 4, l16 = lane & 15;
  int wm = wid >> 1, wn = wid & 1;

  f32x4 acc[4][4];
  f32x4 zero = {0.f, 0.f, 0.f, 0.f};
#pragma unroll
  for (int i = 0; i < 4; ++i)
#pragma unroll
    for (int j = 0; j < 4; ++j) acc[i][j] = zero;
  float biasacc[4] = {0.f, 0.f, 0.f, 0.f};

  for (int s = 0; s < 3; ++s) {
    int e = (s == 2) ? Ee : slotE[b * 4 + s];
    if ((e == 1 && mt == 1) || (e == 2 && mt == 0)) continue;  // masked slot
    float wgt = (s == 2) ? 1.0f : slotW[b * 4 + s];

    const __bf16* Ab = Hbuf + ((size_t)(bl * 3 + s) * Ll + mt * 128) * K + (size_t)kc * KC;
    const __bf16* Bbp = (e < Ee ? W2T + (size_t)e * Dd * K : S2T) + (size_t)(nt * 128) * K + (size_t)kc * KC;

    const __bf16* gp[8];
    uint32_t lo[8];
#pragma unroll
    for (int u = 0; u < 8; ++u) {
      int c = wid * 8 + u;
      int isB = c >> 4;
      int blk = (c & 15) >> 1;
      int ks = c & 1;
      const __bf16* base = isB ? Bbp : Ab;
      gp[u] = base + (size_t)(blk * 16 + l16) * K + ks * 32 + q * 8;
      lo[u] = (uint32_t)(isB * 16384 + (blk * 2 + ks) * 1024);
    }

    // prologue: stage kt=0 into phase 0 (prior slot's last reads of phase 0
    // were protected by its final top-of-loop barrier; LDS dests disjoint)
#pragma unroll
    for (int u = 0; u < 8; ++u) load_lds16(gp[u], smem + lo[u]);

    constexpr int NK = KC / 64;  // 16
    for (int kt = 0; kt < NK; ++kt) {
      int ph = kt & 1;
      __syncthreads();  // drains vmcnt(0): phase ph staging done (full compute phase to land)
      if (kt + 1 < NK) {
#pragma unroll
        for (int u = 0; u < 8; ++u) {
          gp[u] += 64;
          load_lds16(gp[u], smem + lo[u] + (ph ^ 1) * 32768);
        }
      }
      const char* sm = (const char*)smem + ph * 32768;
#pragma unroll
      for (int ks = 0; ks < 2; ++ks) {
        bf16x8 a[4], bb[4];
#pragma unroll
        for (int i = 0; i < 4; ++i)
          a[i] = *(const bf16x8*)(sm + (((wm * 4 + i) * 2 + ks) * 64 + lane) * 16);
#pragma unroll
        for (int j = 0; j < 4; ++j)
          bb[j] = *(const bf16x8*)(sm + 16384 + (((wn * 4 + j) * 2 + ks) * 64 + lane) * 16);
#pragma unroll
        for (int i = 0; i < 4; ++i)
#pragma unroll
          for (int j = 0; j < 4; ++j)
            acc[i][j] = __builtin_amdgcn_mfma_f32_16x16x32_bf16(a[i], bb[j], acc[i][j], 0, 0, 0);
      }
    }

    if (kc == 0) {
      const float* b2p = (e < Ee ? eb2 + e * Dd : sb2);
#pragma unroll
      for (int j = 0; j < 4; ++j)
        biasacc[j] += wgt * b2p[nt * 128 + wn * 64 + j * 16 + l16];
    }
  }

  if (pbuf) {
    // non-atomic bf16 partial store via LDS repack (coalesced bf16x8)
    __syncthreads();
    __bf16* tile = (__bf16*)smem;  // [128][136]
#pragma unroll
    for (int i = 0; i < 4; ++i)
#pragma unroll
      for (int j = 0; j < 4; ++j)
#pragma unroll
        for (int r = 0; r < 4; ++r) {
          int row = wm * 64 + i * 16 + q * 4 + r;
          int col = wn * 64 + j * 16 + l16;
          tile[row * 136 + col] = (__bf16)(acc[i][j][r] + biasacc[j]);
        }
    __syncthreads();
    __bf16* Prow = pbuf + (((size_t)(kc * bc + bl) * Ll + mt * 128)) * Dd + nt * 128;
#pragma unroll
    for (int t2 = 0; t2 < 8; ++t2) {
      int gidx = t2 * 256 + tid;
      int row = gidx >> 4, cg = gidx & 15;
      bf16x8 v = *(const bf16x8*)(tile + row * 136 + cg * 8);
      *(bf16x8*)(Prow + (size_t)row * Dd + cg * 8) = v;
    }
  } else {
    float* orow = out + ((size_t)(b * Ll + mt * 128)) * Dd + nt * 128;
#pragma unroll
    for (int i = 0; i < 4; ++i)
#pragma unroll
      for (int j = 0; j < 4; ++j)
#pragma unroll
        for (int r = 0; r < 4; ++r) {
          int row = wm * 64 + i * 16 + q * 4 + r;
          int col = wn * 64 + j * 16 + l16;
          atomicAdd(orow + (size_t)row * Dd + col, acc[i][j][r] + biasacc[j]);
        }
  }
}

// reduce: out[i] = sum_{kc<4} pbuf[kc][i]  (8 elems/thread)
__global__ void reduce4_kernel(const __bf16* __restrict__ pbuf, float* __restrict__ out,
                               int n8, size_t stride) {
  int i = blockIdx.x * blockDim.x + threadIdx.x;
  if (i >= n8) return;
  size_t base = (size_t)i * 8;
  float sum[8];
#pragma unroll
  for (int k = 0; k < 8; ++k) sum[k] = 0.f;
#pragma unroll
  for (int kc = 0; kc < 4; ++kc) {
    bf16x8 v = *(const bf16x8*)(pbuf + kc * stride + base);
#pragma unroll
    for (int k = 0; k < 8; ++k) sum[k] += (float)v[k];
  }
  float4 o0 = {sum[0], sum[1], sum[2], sum[3]};
  float4 o1 = {sum[4], sum[5], sum[6], sum[7]};
  *(float4*)(out + base) = o0;
  *(float4*)(out + base + 4) = o1;
}

// ---------------- host ----------------

extern "C" void kernel_launch(void* const* d_in, const int* in_sizes, int n_in,
                              void* d_out, int out_size, void* d_ws, size_t ws_size,
                              hipStream_t stream) {
  (void)in_sizes; (void)n_in;
  const float* ctx = (const float*)d_in[0];
  const float* tc  = (const float*)d_in[1];
  const float* gW  = (const float*)d_in[2];
  const float* gb  = (const float*)d_in[3];
  const float* tW  = (const float*)d_in[4];
  const float* tb  = (const float*)d_in[5];
  const float* eW1 = (const float*)d_in[6];
  const float* eb1 = (const float*)d_in[7];
  const float* eW2 = (const float*)d_in[8];
  const float* eb2 = (const float*)d_in[9];
  const float* sW1 = (const float*)d_in[10];
  const float* sb1 = (const float*)d_in[11];
  const float* sW2 = (const float*)d_in[12];
  const float* sb2 = (const float*)d_in[13];
  float* out = (float*)d_out;

  char* ws = (char*)d_ws;
  size_t off = 0;
  auto alloc = [&](size_t sz) { size_t o = off; off += (sz + 255) & ~(size_t)255; return o; };
  size_t oW1T = alloc((size_t)Ee * Hh * Dd * 2);
  size_t oW2T = alloc((size_t)Ee * Dd * Hh * 2);
  size_t oS1T = alloc((size_t)Hh * Dd * 2);
  size_t oS2T = alloc((size_t)Dd * Hh * 2);
  size_t oX   = alloc((size_t)Bb * Ll * Dd * 2);
  size_t oP   = alloc((size_t)Bb * 6 * Dd * 4);
  size_t oSE  = alloc(Bb * 4 * sizeof(int));
  size_t oSW  = alloc(Bb * 4 * sizeof(float));
  size_t fixed = off;

  // plan selection: bc = batches/chunk, use_pbuf = non-atomic partials
  auto hbufB = [&](int bc) { return (size_t)bc * 3 * Ll * Hh * 2; };
  auto pbufB = [&](int bc) { return (size_t)4 * bc * Ll * Dd * 2; };
  int bc = 1; bool use_pbuf = false;
  if (fixed + hbufB(8) + pbufB(8) + 512 <= ws_size)      { bc = 8; use_pbuf = true; }
  else if (fixed + hbufB(4) + pbufB(4) + 512 <= ws_size) { bc = 4; use_pbuf = true; }
  else if (fixed + hbufB(4) + 512 <= ws_size)            { bc = 4; use_pbuf = false; }
  else if (fixed + hbufB(2) + 512 <= ws_size)            { bc = 2; use_pbuf = false; }
  else                                                   { bc = 1; use_pbuf = false; }
  int nchunk = Bb / bc;
  size_t oH = alloc(hbufB(bc));
  size_t oPB = use_pbuf ? alloc(pbufB(bc)) : 0;

  __bf16* W1T = (__bf16*)(ws + oW1T);
  __bf16* W2T = (__bf16*)(ws + oW2T);
  __bf16* S1T = (__bf16*)(ws + oS1T);
  __bf16* S2T = (__bf16*)(ws + oS2T);
  __bf16* Xbf = (__bf16*)(ws + oX);
  float*  part = (float*)(ws + oP);
  int*    slotE = (int*)(ws + oSE);
  float*  slotW = (float*)(ws + oSW);
  __bf16* Hbuf = (__bf16*)(ws + oH);
  __bf16* Pbuf = use_pbuf ? (__bf16*)(ws + oPB) : nullptr;

  // pbuf path fully overwrites out via reduce4 -> memset only needed for atomics
  if (!use_pbuf)
    hipMemsetAsync(d_out, 0, (size_t)out_size * sizeof(float), stream);

  cvt_x_kernel<<<(Bb * Ll * Dd / 4 + 255) / 256, 256, 0, stream>>>(ctx, Xbf, Bb * Ll * Dd / 4);
  transpose_cvt_kernel<<<dim3(Hh / 32, Dd / 32, Ee), 256, 0, stream>>>(eW1, W1T, Dd, Hh);
  transpose_cvt_kernel<<<dim3(Dd / 32, Hh / 32, Ee), 256, 0, stream>>>(eW2, W2T, Hh, Dd);
  transpose_cvt_kernel<<<dim3(Hh / 32, Dd / 32, 1), 256, 0, stream>>>(sW1, S1T, Dd, Hh);
  transpose_cvt_kernel<<<dim3(Dd / 32, Hh / 32, 1), 256, 0, stream>>>(sW2, S2T, Hh, Dd);
  agg_kernel<<<dim3(6, Bb), 256, 0, stream>>>(ctx, part);
  gate_kernel<<<Bb, 256, 0, stream>>>(part, tc, gW, gb, tW, tb, slotE, slotW);

  for (int c = 0; c < nchunk; ++c) {
    gemm1_kernel<<<dim3(Hh / 128, 3, bc * 3), 256, 0, stream>>>(
        Xbf, W1T, S1T, eb1, sb1, slotE, slotW, Hbuf, c * bc);
    gemm2_kernel<<<dim3(Dd / 128, 3, bc * 4), 256, 0, stream>>>(
        Hbuf, W2T, S2T, eb2, sb2, slotE, slotW, out, Pbuf, c * bc, bc);
    if (use_pbuf) {
      int n8 = bc * Ll * Dd / 8;
      reduce4_kernel<<<(n8 + 255) / 256, 256, 0, stream>>>(
          Pbuf, out + (size_t)c * bc * Ll * Dd, n8, (size_t)bc * Ll * Dd);
    }
  }
}

// Round 4
// 563.190 us; speedup vs baseline: 1.3910x; 1.0321x over previous
//
#include <hip/hip_runtime.h>
#include <cstdint>
#include <cstddef>

// ModalityMoE: B=8, L=384, D=1024, E=4, K=2, H=4096
// R6 (resubmit; previous attempt hit "container failed twice" infra error,
// kernel re-audited: swizzle bijective, no OOB, dbuf slot-boundary race-free).
// Theory: gemm2 181us, MfmaUtil 15.5%, FETCH 340MB @ 2.06TB/s, both pipes
// idle -> miss-latency bound; panel sharers round-robin across XCDs so reuse
// misses the local L2. Also 768 blocks / 512 resident slots = 1.5 rounds ->
// ~25% makespan tail. Fix: (1) T1 chunked XCD swizzle, 1-D grid, nt-fastest
// decomposition (chunk = one batch per XCD); (2) gemm2 K-split 4->8 (KC=512)
// -> 1536 blocks = 3.0 exact rounds. Index-only changes vs R5.

#define DEV __device__ __forceinline__

typedef __attribute__((ext_vector_type(8))) __bf16 bf16x8;
typedef __attribute__((ext_vector_type(4))) __bf16 bf16x4;
typedef __attribute__((ext_vector_type(4))) float f32x4;

static constexpr int Bb = 8, Ll = 384, Dd = 1024, Ee = 4, Hh = 4096;

DEV void load_lds16(const void* g, void* l) {
  __builtin_amdgcn_global_load_lds(
      (const __attribute__((address_space(1))) void*)g,
      (__attribute__((address_space(3))) void*)l, 16, 0, 0);
}

DEV float gelu_tanh(float x) {
  float u = 0.7978845608028654f * (x + 0.044715f * x * x * x);
  float t = 1.0f - 2.0f / (1.0f + __expf(2.0f * u));
  return 0.5f * x * (1.0f + t);
}

DEV float wave_red(float v) {
#pragma unroll
  for (int o = 32; o > 0; o >>= 1) v += __shfl_down(v, o, 64);
  return v;
}

// ---------------- conversion / transpose ----------------

__global__ void cvt_x_kernel(const float* __restrict__ src, __bf16* __restrict__ dst, int n4) {
  int i = blockIdx.x * blockDim.x + threadIdx.x;
  if (i >= n4) return;
  float4 v = ((const float4*)src)[i];
  bf16x4 o;
  o.x = (__bf16)v.x; o.y = (__bf16)v.y; o.z = (__bf16)v.z; o.w = (__bf16)v.w;
  ((bf16x4*)dst)[i] = o;
}

// src: [bz][nr][nc] fp32 -> dst: [bz][nc][nr] bf16
__global__ void transpose_cvt_kernel(const float* __restrict__ src, __bf16* __restrict__ dst,
                                     int nr, int nc) {
  __shared__ float t[32][33];
  size_t base = (size_t)blockIdx.z * nr * nc;
  src += base; dst += base;
  int x = threadIdx.x & 31, y = threadIdx.x >> 5;
  int c0 = blockIdx.x * 32, r0 = blockIdx.y * 32;
#pragma unroll
  for (int r = 0; r < 4; ++r) {
    int rr = y + r * 8;
    t[rr][x] = src[(size_t)(r0 + rr) * nc + c0 + x];
  }
  __syncthreads();
#pragma unroll
  for (int r = 0; r < 4; ++r) {
    int rr = y + r * 8;
    dst[(size_t)(c0 + rr) * nr + r0 + x] = (__bf16)t[x][rr];
  }
}

// ---------------- gating ----------------

__global__ void agg_kernel(const float* __restrict__ ctx, float* __restrict__ part) {
  int c = blockIdx.x, b = blockIdx.y, t = threadIdx.x;
  int d0 = t * 4;
  float4 sum = {0.f, 0.f, 0.f, 0.f};
  const float* p = ctx + ((size_t)(b * Ll + c * 64)) * Dd + d0;
  for (int l = 0; l < 64; ++l) {
    float4 v = *(const float4*)(p + (size_t)l * Dd);
    sum.x += v.x; sum.y += v.y; sum.z += v.z; sum.w += v.w;
  }
  *(float4*)(part + ((size_t)(b * 6 + c)) * Dd + d0) = sum;
}

__global__ void gate_kernel(const float* __restrict__ part, const float* __restrict__ tc,
                            const float* __restrict__ gW, const float* __restrict__ gb,
                            const float* __restrict__ tW, const float* __restrict__ tb,
                            int* __restrict__ slotE, float* __restrict__ slotW) {
  __shared__ float gi[3 * Dd];
  __shared__ float st[Dd];
  __shared__ float red[12];
  int b = blockIdx.x, t = threadIdx.x;
  const float* pb = part + (size_t)b * 6 * Dd;
#pragma unroll
  for (int k = 0; k < 4; ++k) {
    int d = t * 4 + k;
    float p0 = pb[d], p1 = pb[Dd + d], p2 = pb[2 * Dd + d];
    float p3 = pb[3 * Dd + d], p4 = pb[4 * Dd + d], p5 = pb[5 * Dd + d];
    gi[d]          = (p0 + p1 + p2 + p3 + p4 + p5) * (1.0f / 384.0f);
    gi[Dd + d]     = (p0 + p1 + p4 + p5) * (1.0f / 256.0f);
    gi[2 * Dd + d] = (p2 + p3 + p4 + p5) * (1.0f / 256.0f);
    float tv = tc[b * Dd + d];
    st[d] = tv / (1.0f + __expf(-tv));
  }
  __syncthreads();
  int wid = t >> 6, lane = t & 63;
  float aL = 0.f;
  for (int i = lane; i < 3 * Dd; i += 64) aL += gi[i] * gW[wid * 3 * Dd + i];
  aL = wave_red(aL);
  float aA = 0.f, aB = 0.f;
  for (int i = lane; i < Dd; i += 64) {
    float s = st[i];
    aA += s * tW[wid * Dd + i];
    aB += s * tW[(wid + 4) * Dd + i];
  }
  aA = wave_red(aA); aB = wave_red(aB);
  if (lane == 0) { red[wid] = aL; red[4 + wid] = aA; red[8 + wid] = aB; }
  __syncthreads();
  if (t == 0) {
    float lg[4];
#pragma unroll
    for (int e = 0; e < 4; ++e) {
      float logit = red[e] + gb[e];
      float scale = red[4 + e] + tb[e];
      float shift = red[8 + e] + tb[4 + e];
      lg[e] = logit * (1.0f + scale) + shift;
    }
    float m = fmaxf(fmaxf(lg[0], lg[1]), fmaxf(lg[2], lg[3]));
    float p[4], sum = 0.f;
#pragma unroll
    for (int e = 0; e < 4; ++e) { p[e] = __expf(lg[e] - m); sum += p[e]; }
#pragma unroll
    for (int e = 0; e < 4; ++e) p[e] /= sum;
    int i0 = 0;
    for (int e = 1; e < 4; ++e) if (p[e] > p[i0]) i0 = e;
    int i1 = -1;
    for (int e = 0; e < 4; ++e) if (e != i0 && (i1 < 0 || p[e] > p[i1])) i1 = e;
    float sw = p[i0] + p[i1] + 1e-8f;
    slotE[b * 4 + 0] = i0; slotE[b * 4 + 1] = i1;
    slotW[b * 4 + 0] = p[i0] / sw; slotW[b * 4 + 1] = p[i1] / sw;
  }
}

// ---- GEMM1: H = w * gelu(X @ W1 + b1), bf16 out; dbuf + XCD swizzle ----
// 1-D grid, logical id decomposed nt-fastest: lid = nt + 32*(mt + 3*(s + 3*bl))
// chunked swizzle => one XCD covers one bl (all nt,mt,s): A-panels and
// B-col-panels get same-XCD L2 temporal reuse.

__global__ __launch_bounds__(256) void gemm1_kernel(
    const __bf16* __restrict__ Xbf, const __bf16* __restrict__ W1T,
    const __bf16* __restrict__ S1T, const float* __restrict__ eb1,
    const float* __restrict__ sb1, const int* __restrict__ slotE,
    const float* __restrict__ slotW, __bf16* __restrict__ Hbuf, int bbase) {
  constexpr int K = Dd;  // 1024
  int bid = blockIdx.x, nwg = gridDim.x;
  int lid = (bid & 7) * (nwg >> 3) + (bid >> 3);  // XCD-chunked (nwg % 8 == 0)
  int nt = lid & 31;
  int r = lid >> 5;
  int mt = r % 3; r /= 3;
  int s = r % 3;
  int bl = r / 3;
  int b = bbase + bl;
  int e = (s == 2) ? Ee : slotE[b * 4 + s];
  if ((e == 1 && mt == 1) || (e == 2 && mt == 0)) return;  // mask-aligned skip
  float wgt = (s == 2) ? 1.0f : slotW[b * 4 + s];

  const __bf16* Ab = Xbf + ((size_t)(b * Ll + mt * 128)) * K;
  const __bf16* Bbp = (e < Ee ? W1T + (size_t)e * Hh * K : S1T) + (size_t)(nt * 128) * K;
  const float* b1p = (e < Ee ? eb1 + e * Hh : sb1);

  __shared__ __align__(16) char smem[65536];  // 2 phases x (16KB A + 16KB B)

  int tid = threadIdx.x, wid = tid >> 6, lane = tid & 63;
  int q = lane >> 4, l16 = lane & 15;
  int wm = wid >> 1, wn = wid & 1;

  const __bf16* gp[8];
  uint32_t lo[8];
#pragma unroll
  for (int u = 0; u < 8; ++u) {
    int c = wid * 8 + u;
    int isB = c >> 4;
    int blk = (c & 15) >> 1;
    int ks = c & 1;
    const __bf16* base = isB ? Bbp : Ab;
    gp[u] = base + (size_t)(blk * 16 + l16) * K + ks * 32 + q * 8;
    lo[u] = (uint32_t)(isB * 16384 + (blk * 2 + ks) * 1024);
  }

  f32x4 acc[4][4];
  f32x4 zero = {0.f, 0.f, 0.f, 0.f};
#pragma unroll
  for (int i = 0; i < 4; ++i)
#pragma unroll
    for (int j = 0; j < 4; ++j) acc[i][j] = zero;

  // prologue: stage kt=0 into phase 0
#pragma unroll
  for (int u = 0; u < 8; ++u) load_lds16(gp[u], smem + lo[u]);

  constexpr int NK = K / 64;  // 16
  for (int kt = 0; kt < NK; ++kt) {
    int ph = kt & 1;
    __syncthreads();  // drains vmcnt(0): phase ph staging (issued last iter) done
    if (kt + 1 < NK) {
#pragma unroll
      for (int u = 0; u < 8; ++u) {
        gp[u] += 64;
        load_lds16(gp[u], smem + lo[u] + (ph ^ 1) * 32768);
      }
    }
    const char* sm = (const char*)smem + ph * 32768;
#pragma unroll
    for (int ks = 0; ks < 2; ++ks) {
      bf16x8 a[4], bb[4];
#pragma unroll
      for (int i = 0; i < 4; ++i)
        a[i] = *(const bf16x8*)(sm + (((wm * 4 + i) * 2 + ks) * 64 + lane) * 16);
#pragma unroll
      for (int j = 0; j < 4; ++j)
        bb[j] = *(const bf16x8*)(sm + 16384 + (((wn * 4 + j) * 2 + ks) * 64 + lane) * 16);
#pragma unroll
      for (int i = 0; i < 4; ++i)
#pragma unroll
        for (int j = 0; j < 4; ++j)
          acc[i][j] = __builtin_amdgcn_mfma_f32_16x16x32_bf16(a[i], bb[j], acc[i][j], 0, 0, 0);
    }
  }

  float bias[4];
#pragma unroll
  for (int j = 0; j < 4; ++j) bias[j] = b1p[nt * 128 + wn * 64 + j * 16 + l16];

  __syncthreads();
  __bf16* tile = (__bf16*)smem;  // [128][136]
#pragma unroll
  for (int i = 0; i < 4; ++i)
#pragma unroll
    for (int j = 0; j < 4; ++j)
#pragma unroll
      for (int r2 = 0; r2 < 4; ++r2) {
        float x = acc[i][j][r2] + bias[j];
        int row = wm * 64 + i * 16 + q * 4 + r2;
        int col = wn * 64 + j * 16 + l16;
        tile[row * 136 + col] = (__bf16)(wgt * gelu_tanh(x));
      }
  __syncthreads();
  __bf16* Hrow = Hbuf + ((size_t)(bl * 3 + s) * Ll + mt * 128) * Hh + nt * 128;
#pragma unroll
  for (int t2 = 0; t2 < 8; ++t2) {
    int gidx = t2 * 256 + tid;
    int row = gidx >> 4, cg = gidx & 15;
    bf16x8 v = *(const bf16x8*)(tile + row * 136 + cg * 8);
    *(bf16x8*)(Hrow + (size_t)row * Hh + cg * 8) = v;
  }
}

// ---- GEMM2: per-slot dbuf K-loop; KC template (512/1024); XCD swizzle ----
// lid = nt + 8*(mt + 3*(kc + NKC*bl)), chunk = one bl per XCD.

template <int KC>
__global__ __launch_bounds__(256) void gemm2_kernel(
    const __bf16* __restrict__ Hbuf, const __bf16* __restrict__ W2T,
    const __bf16* __restrict__ S2T, const float* __restrict__ eb2,
    const float* __restrict__ sb2, const int* __restrict__ slotE,
    const float* __restrict__ slotW, float* __restrict__ out,
    __bf16* __restrict__ pbuf, int bbase, int bc) {
  constexpr int K = Hh;          // 4096 total
  constexpr int NKC = Hh / KC;   // K chunks (4 or 8)
  int bid = blockIdx.x, nwg = gridDim.x;
  int lid = (bid & 7) * (nwg >> 3) + (bid >> 3);  // XCD-chunked (nwg % 8 == 0)
  int nt = lid & 7;
  int r = lid >> 3;
  int mt = r % 3; r /= 3;
  int kc = r % NKC;
  int bl = r / NKC;
  int b = bbase + bl;

  __shared__ __align__(16) char smem[65536];

  int tid = threadIdx.x, wid = tid >> 6, lane = tid & 63;
  int q = lane >> 4, l16 = lane & 15;
  int wm = wid >> 1, wn = wid & 1;

  f32x4 acc[4][4];
  f32x4 zero = {0.f, 0.f, 0.f, 0.f};
#pragma unroll
  for (int i = 0; i < 4; ++i)
#pragma unroll
    for (int j = 0; j < 4; ++j) acc[i][j] = zero;
  float biasacc[4] = {0.f, 0.f, 0.f, 0.f};

  for (int s = 0; s < 3; ++s) {
    int e = (s == 2) ? Ee : slotE[b * 4 + s];
    if ((e == 1 && mt == 1) || (e == 2 && mt == 0)) continue;  // masked slot
    float wgt = (s == 2) ? 1.0f : slotW[b * 4 + s];

    const __bf16* Ab = Hbuf + ((size_t)(bl * 3 + s) * Ll + mt * 128) * K + (size_t)kc * KC;
    const __bf16* Bbp = (e < Ee ? W2T + (size_t)e * Dd * K : S2T) + (size_t)(nt * 128) * K + (size_t)kc * KC;

    const __bf16* gp[8];
    uint32_t lo[8];
#pragma unroll
    for (int u = 0; u < 8; ++u) {
      int c = wid * 8 + u;
      int isB = c >> 4;
      int blk = (c & 15) >> 1;
      int ks = c & 1;
      const __bf16* base = isB ? Bbp : Ab;
      gp[u] = base + (size_t)(blk * 16 + l16) * K + ks * 32 + q * 8;
      lo[u] = (uint32_t)(isB * 16384 + (blk * 2 + ks) * 1024);
    }

    // prologue: stage kt=0 into phase 0 (prior slot's last phase-0 reads were
    // protected by its final top-of-loop barrier; LDS dests disjoint)
#pragma unroll
    for (int u = 0; u < 8; ++u) load_lds16(gp[u], smem + lo[u]);

    constexpr int NK = KC / 64;  // 8 or 16
    for (int kt = 0; kt < NK; ++kt) {
      int ph = kt & 1;
      __syncthreads();  // drains vmcnt(0): phase ph staging done
      if (kt + 1 < NK) {
#pragma unroll
        for (int u = 0; u < 8; ++u) {
          gp[u] += 64;
          load_lds16(gp[u], smem + lo[u] + (ph ^ 1) * 32768);
        }
      }
      const char* sm = (const char*)smem + ph * 32768;
#pragma unroll
      for (int ks = 0; ks < 2; ++ks) {
        bf16x8 a[4], bb[4];
#pragma unroll
        for (int i = 0; i < 4; ++i)
          a[i] = *(const bf16x8*)(sm + (((wm * 4 + i) * 2 + ks) * 64 + lane) * 16);
#pragma unroll
        for (int j = 0; j < 4; ++j)
          bb[j] = *(const bf16x8*)(sm + 16384 + (((wn * 4 + j) * 2 + ks) * 64 + lane) * 16);
#pragma unroll
        for (int i = 0; i < 4; ++i)
#pragma unroll
          for (int j = 0; j < 4; ++j)
            acc[i][j] = __builtin_amdgcn_mfma_f32_16x16x32_bf16(a[i], bb[j], acc[i][j], 0, 0, 0);
      }
    }

    if (kc == 0) {
      const float* b2p = (e < Ee ? eb2 + e * Dd : sb2);
#pragma unroll
      for (int j = 0; j < 4; ++j)
        biasacc[j] += wgt * b2p[nt * 128 + wn * 64 + j * 16 + l16];
    }
  }

  if (pbuf) {
    // non-atomic bf16 partial store via LDS repack (coalesced bf16x8)
    __syncthreads();
    __bf16* tile = (__bf16*)smem;  // [128][136]
#pragma unroll
    for (int i = 0; i < 4; ++i)
#pragma unroll
      for (int j = 0; j < 4; ++j)
#pragma unroll
        for (int r2 = 0; r2 < 4; ++r2) {
          int row = wm * 64 + i * 16 + q * 4 + r2;
          int col = wn * 64 + j * 16 + l16;
          tile[row * 136 + col] = (__bf16)(acc[i][j][r2] + biasacc[j]);
        }
    __syncthreads();
    __bf16* Prow = pbuf + (((size_t)(kc * bc + bl) * Ll + mt * 128)) * Dd + nt * 128;
#pragma unroll
    for (int t2 = 0; t2 < 8; ++t2) {
      int gidx = t2 * 256 + tid;
      int row = gidx >> 4, cg = gidx & 15;
      bf16x8 v = *(const bf16x8*)(tile + row * 136 + cg * 8);
      *(bf16x8*)(Prow + (size_t)row * Dd + cg * 8) = v;
    }
  } else {
    float* orow = out + ((size_t)(b * Ll + mt * 128)) * Dd + nt * 128;
#pragma unroll
    for (int i = 0; i < 4; ++i)
#pragma unroll
      for (int j = 0; j < 4; ++j)
#pragma unroll
        for (int r2 = 0; r2 < 4; ++r2) {
          int row = wm * 64 + i * 16 + q * 4 + r2;
          int col = wn * 64 + j * 16 + l16;
          atomicAdd(orow + (size_t)row * Dd + col, acc[i][j][r2] + biasacc[j]);
        }
  }
}

// reduce: out[i] = sum_{kc<nkc} pbuf[kc][i]  (8 elems/thread)
__global__ void reduce_kernel(const __bf16* __restrict__ pbuf, float* __restrict__ out,
                              int n8, size_t stride, int nkc) {
  int i = blockIdx.x * blockDim.x + threadIdx.x;
  if (i >= n8) return;
  size_t base = (size_t)i * 8;
  float sum[8];
#pragma unroll
  for (int k = 0; k < 8; ++k) sum[k] = 0.f;
  for (int kc = 0; kc < nkc; ++kc) {
    bf16x8 v = *(const bf16x8*)(pbuf + kc * stride + base);
#pragma unroll
    for (int k = 0; k < 8; ++k) sum[k] += (float)v[k];
  }
  float4 o0 = {sum[0], sum[1], sum[2], sum[3]};
  float4 o1 = {sum[4], sum[5], sum[6], sum[7]};
  *(float4*)(out + base) = o0;
  *(float4*)(out + base + 4) = o1;
}

// ---------------- host ----------------

extern "C" void kernel_launch(void* const* d_in, const int* in_sizes, int n_in,
                              void* d_out, int out_size, void* d_ws, size_t ws_size,
                              hipStream_t stream) {
  (void)in_sizes; (void)n_in;
  const float* ctx = (const float*)d_in[0];
  const float* tc  = (const float*)d_in[1];
  const float* gW  = (const float*)d_in[2];
  const float* gb  = (const float*)d_in[3];
  const float* tW  = (const float*)d_in[4];
  const float* tb  = (const float*)d_in[5];
  const float* eW1 = (const float*)d_in[6];
  const float* eb1 = (const float*)d_in[7];
  const float* eW2 = (const float*)d_in[8];
  const float* eb2 = (const float*)d_in[9];
  const float* sW1 = (const float*)d_in[10];
  const float* sb1 = (const float*)d_in[11];
  const float* sW2 = (const float*)d_in[12];
  const float* sb2 = (const float*)d_in[13];
  float* out = (float*)d_out;

  char* ws = (char*)d_ws;
  size_t off = 0;
  auto alloc = [&](size_t sz) { size_t o = off; off += (sz + 255) & ~(size_t)255; return o; };
  size_t oW1T = alloc((size_t)Ee * Hh * Dd * 2);
  size_t oW2T = alloc((size_t)Ee * Dd * Hh * 2);
  size_t oS1T = alloc((size_t)Hh * Dd * 2);
  size_t oS2T = alloc((size_t)Dd * Hh * 2);
  size_t oX   = alloc((size_t)Bb * Ll * Dd * 2);
  size_t oP   = alloc((size_t)Bb * 6 * Dd * 4);
  size_t oSE  = alloc(Bb * 4 * sizeof(int));
  size_t oSW  = alloc(Bb * 4 * sizeof(float));
  size_t fixed = off;

  // plan selection: bc = batches/chunk, nkc = gemm2 K-split, use_pbuf = non-atomic
  auto hbufB = [&](int bc) { return (size_t)bc * 3 * Ll * Hh * 2; };
  auto pbufB = [&](int bc, int nkc) { return (size_t)nkc * bc * Ll * Dd * 2; };
  int bc = 1; bool use_pbuf = false; int nkc = 4;
  if (fixed + hbufB(8) + pbufB(8, 8) + 512 <= ws_size)      { bc = 8; use_pbuf = true; nkc = 8; }
  else if (fixed + hbufB(8) + pbufB(8, 4) + 512 <= ws_size) { bc = 8; use_pbuf = true; nkc = 4; }
  else if (fixed + hbufB(4) + pbufB(4, 4) + 512 <= ws_size) { bc = 4; use_pbuf = true; nkc = 4; }
  else if (fixed + hbufB(4) + 512 <= ws_size)               { bc = 4; use_pbuf = false; nkc = 4; }
  else if (fixed + hbufB(2) + 512 <= ws_size)               { bc = 2; use_pbuf = false; nkc = 4; }
  else                                                      { bc = 1; use_pbuf = false; nkc = 4; }
  int nchunk = Bb / bc;
  size_t oH = alloc(hbufB(bc));
  size_t oPB = use_pbuf ? alloc(pbufB(bc, nkc)) : 0;

  __bf16* W1T = (__bf16*)(ws + oW1T);
  __bf16* W2T = (__bf16*)(ws + oW2T);
  __bf16* S1T = (__bf16*)(ws + oS1T);
  __bf16* S2T = (__bf16*)(ws + oS2T);
  __bf16* Xbf = (__bf16*)(ws + oX);
  float*  part = (float*)(ws + oP);
  int*    slotE = (int*)(ws + oSE);
  float*  slotW = (float*)(ws + oSW);
  __bf16* Hbuf = (__bf16*)(ws + oH);
  __bf16* Pbuf = use_pbuf ? (__bf16*)(ws + oPB) : nullptr;

  // pbuf path fully overwrites out via reduce -> memset only needed for atomics
  if (!use_pbuf)
    hipMemsetAsync(d_out, 0, (size_t)out_size * sizeof(float), stream);

  cvt_x_kernel<<<(Bb * Ll * Dd / 4 + 255) / 256, 256, 0, stream>>>(ctx, Xbf, Bb * Ll * Dd / 4);
  transpose_cvt_kernel<<<dim3(Hh / 32, Dd / 32, Ee), 256, 0, stream>>>(eW1, W1T, Dd, Hh);
  transpose_cvt_kernel<<<dim3(Dd / 32, Hh / 32, Ee), 256, 0, stream>>>(eW2, W2T, Hh, Dd);
  transpose_cvt_kernel<<<dim3(Hh / 32, Dd / 32, 1), 256, 0, stream>>>(sW1, S1T, Dd, Hh);
  transpose_cvt_kernel<<<dim3(Dd / 32, Hh / 32, 1), 256, 0, stream>>>(sW2, S2T, Hh, Dd);
  agg_kernel<<<dim3(6, Bb), 256, 0, stream>>>(ctx, part);
  gate_kernel<<<Bb, 256, 0, stream>>>(part, tc, gW, gb, tW, tb, slotE, slotW);

  for (int c = 0; c < nchunk; ++c) {
    // gemm1: 1-D grid, 288 blocks per batch (32 nt x 3 mt x 3 s), %8==0
    gemm1_kernel<<<dim3(288 * bc), 256, 0, stream>>>(
        Xbf, W1T, S1T, eb1, sb1, slotE, slotW, Hbuf, c * bc);
    // gemm2: 1-D grid, 8 nt x 3 mt x nkc x bc, %8==0
    int g2 = 8 * 3 * nkc * bc;
    if (nkc == 8)
      gemm2_kernel<512><<<dim3(g2), 256, 0, stream>>>(
          Hbuf, W2T, S2T, eb2, sb2, slotE, slotW, out, Pbuf, c * bc, bc);
    else
      gemm2_kernel<1024><<<dim3(g2), 256, 0, stream>>>(
          Hbuf, W2T, S2T, eb2, sb2, slotE, slotW, out, Pbuf, c * bc, bc);
    if (use_pbuf) {
      int n8 = bc * Ll * Dd / 8;
      reduce_kernel<<<(n8 + 255) / 256, 256, 0, stream>>>(
          Pbuf, out + (size_t)c * bc * Ll * Dd, n8, (size_t)bc * Ll * Dd, nkc);
    }
  }
}

// Round 5
// 549.091 us; speedup vs baseline: 1.4267x; 1.0257x over previous
//
#include <hip/hip_runtime.h>
#include <cstdint>
#include <cstddef>

// ModalityMoE: B=8, L=384, D=1024, E=4, K=2, H=4096
// R7: occupancy over dbuf. Evidence (R6): gemm1 171us is now the top kernel;
// FETCH 218MB = 8 XCDs x unique working set (swizzle: L2 reuse ~perfect) yet
// only 1.7TB/s / MfmaUtil 17% -> latency-exposed, not BW-bound. Depth-1 dbuf
// covers ~300cyc of ~900cyc step; 64KB LDS caps TLP at 2 blocks/CU. R5 A/B
// showed dbuf ~= single-buf (-2%). Fix: revert both GEMMs to the R3-proven
// single-buffer 34816B 2-barrier loop -> 4 blocks/CU (+launch_bounds(256,4)).
// Swizzle, nkc=8, pbuf path unchanged.

#define DEV __device__ __forceinline__

typedef __attribute__((ext_vector_type(8))) __bf16 bf16x8;
typedef __attribute__((ext_vector_type(4))) __bf16 bf16x4;
typedef __attribute__((ext_vector_type(4))) float f32x4;

static constexpr int Bb = 8, Ll = 384, Dd = 1024, Ee = 4, Hh = 4096;

DEV void load_lds16(const void* g, void* l) {
  __builtin_amdgcn_global_load_lds(
      (const __attribute__((address_space(1))) void*)g,
      (__attribute__((address_space(3))) void*)l, 16, 0, 0);
}

DEV float gelu_tanh(float x) {
  float u = 0.7978845608028654f * (x + 0.044715f * x * x * x);
  float t = 1.0f - 2.0f / (1.0f + __expf(2.0f * u));
  return 0.5f * x * (1.0f + t);
}

DEV float wave_red(float v) {
#pragma unroll
  for (int o = 32; o > 0; o >>= 1) v += __shfl_down(v, o, 64);
  return v;
}

// ---------------- conversion / transpose ----------------

__global__ void cvt_x_kernel(const float* __restrict__ src, __bf16* __restrict__ dst, int n4) {
  int i = blockIdx.x * blockDim.x + threadIdx.x;
  if (i >= n4) return;
  float4 v = ((const float4*)src)[i];
  bf16x4 o;
  o.x = (__bf16)v.x; o.y = (__bf16)v.y; o.z = (__bf16)v.z; o.w = (__bf16)v.w;
  ((bf16x4*)dst)[i] = o;
}

// src: [bz][nr][nc] fp32 -> dst: [bz][nc][nr] bf16
__global__ void transpose_cvt_kernel(const float* __restrict__ src, __bf16* __restrict__ dst,
                                     int nr, int nc) {
  __shared__ float t[32][33];
  size_t base = (size_t)blockIdx.z * nr * nc;
  src += base; dst += base;
  int x = threadIdx.x & 31, y = threadIdx.x >> 5;
  int c0 = blockIdx.x * 32, r0 = blockIdx.y * 32;
#pragma unroll
  for (int r = 0; r < 4; ++r) {
    int rr = y + r * 8;
    t[rr][x] = src[(size_t)(r0 + rr) * nc + c0 + x];
  }
  __syncthreads();
#pragma unroll
  for (int r = 0; r < 4; ++r) {
    int rr = y + r * 8;
    dst[(size_t)(c0 + rr) * nr + r0 + x] = (__bf16)t[x][rr];
  }
}

// ---------------- gating ----------------

__global__ void agg_kernel(const float* __restrict__ ctx, float* __restrict__ part) {
  int c = blockIdx.x, b = blockIdx.y, t = threadIdx.x;
  int d0 = t * 4;
  float4 sum = {0.f, 0.f, 0.f, 0.f};
  const float* p = ctx + ((size_t)(b * Ll + c * 64)) * Dd + d0;
  for (int l = 0; l < 64; ++l) {
    float4 v = *(const float4*)(p + (size_t)l * Dd);
    sum.x += v.x; sum.y += v.y; sum.z += v.z; sum.w += v.w;
  }
  *(float4*)(part + ((size_t)(b * 6 + c)) * Dd + d0) = sum;
}

__global__ void gate_kernel(const float* __restrict__ part, const float* __restrict__ tc,
                            const float* __restrict__ gW, const float* __restrict__ gb,
                            const float* __restrict__ tW, const float* __restrict__ tb,
                            int* __restrict__ slotE, float* __restrict__ slotW) {
  __shared__ float gi[3 * Dd];
  __shared__ float st[Dd];
  __shared__ float red[12];
  int b = blockIdx.x, t = threadIdx.x;
  const float* pb = part + (size_t)b * 6 * Dd;
#pragma unroll
  for (int k = 0; k < 4; ++k) {
    int d = t * 4 + k;
    float p0 = pb[d], p1 = pb[Dd + d], p2 = pb[2 * Dd + d];
    float p3 = pb[3 * Dd + d], p4 = pb[4 * Dd + d], p5 = pb[5 * Dd + d];
    gi[d]          = (p0 + p1 + p2 + p3 + p4 + p5) * (1.0f / 384.0f);
    gi[Dd + d]     = (p0 + p1 + p4 + p5) * (1.0f / 256.0f);
    gi[2 * Dd + d] = (p2 + p3 + p4 + p5) * (1.0f / 256.0f);
    float tv = tc[b * Dd + d];
    st[d] = tv / (1.0f + __expf(-tv));
  }
  __syncthreads();
  int wid = t >> 6, lane = t & 63;
  float aL = 0.f;
  for (int i = lane; i < 3 * Dd; i += 64) aL += gi[i] * gW[wid * 3 * Dd + i];
  aL = wave_red(aL);
  float aA = 0.f, aB = 0.f;
  for (int i = lane; i < Dd; i += 64) {
    float s = st[i];
    aA += s * tW[wid * Dd + i];
    aB += s * tW[(wid + 4) * Dd + i];
  }
  aA = wave_red(aA); aB = wave_red(aB);
  if (lane == 0) { red[wid] = aL; red[4 + wid] = aA; red[8 + wid] = aB; }
  __syncthreads();
  if (t == 0) {
    float lg[4];
#pragma unroll
    for (int e = 0; e < 4; ++e) {
      float logit = red[e] + gb[e];
      float scale = red[4 + e] + tb[e];
      float shift = red[8 + e] + tb[4 + e];
      lg[e] = logit * (1.0f + scale) + shift;
    }
    float m = fmaxf(fmaxf(lg[0], lg[1]), fmaxf(lg[2], lg[3]));
    float p[4], sum = 0.f;
#pragma unroll
    for (int e = 0; e < 4; ++e) { p[e] = __expf(lg[e] - m); sum += p[e]; }
#pragma unroll
    for (int e = 0; e < 4; ++e) p[e] /= sum;
    int i0 = 0;
    for (int e = 1; e < 4; ++e) if (p[e] > p[i0]) i0 = e;
    int i1 = -1;
    for (int e = 0; e < 4; ++e) if (e != i0 && (i1 < 0 || p[e] > p[i1])) i1 = e;
    float sw = p[i0] + p[i1] + 1e-8f;
    slotE[b * 4 + 0] = i0; slotE[b * 4 + 1] = i1;
    slotW[b * 4 + 0] = p[i0] / sw; slotW[b * 4 + 1] = p[i1] / sw;
  }
}

// ---- GEMM1: H = w * gelu(X @ W1 + b1); single-buf 34KB, XCD swizzle ----
// 1-D grid, lid = nt + 32*(mt + 3*(s + 3*bl)); chunk = one bl per XCD.

__global__ __launch_bounds__(256, 4) void gemm1_kernel(
    const __bf16* __restrict__ Xbf, const __bf16* __restrict__ W1T,
    const __bf16* __restrict__ S1T, const float* __restrict__ eb1,
    const float* __restrict__ sb1, const int* __restrict__ slotE,
    const float* __restrict__ slotW, __bf16* __restrict__ Hbuf, int bbase) {
  constexpr int K = Dd;  // 1024
  int bid = blockIdx.x, nwg = gridDim.x;
  int lid = (bid & 7) * (nwg >> 3) + (bid >> 3);  // XCD-chunked (nwg % 8 == 0)
  int nt = lid & 31;
  int r = lid >> 5;
  int mt = r % 3; r /= 3;
  int s = r % 3;
  int bl = r / 3;
  int b = bbase + bl;
  int e = (s == 2) ? Ee : slotE[b * 4 + s];
  if ((e == 1 && mt == 1) || (e == 2 && mt == 0)) return;  // mask-aligned skip
  float wgt = (s == 2) ? 1.0f : slotW[b * 4 + s];

  const __bf16* Ab = Xbf + ((size_t)(b * Ll + mt * 128)) * K;
  const __bf16* Bbp = (e < Ee ? W1T + (size_t)e * Hh * K : S1T) + (size_t)(nt * 128) * K;
  const float* b1p = (e < Ee ? eb1 + e * Hh : sb1);

  __shared__ __align__(16) char smem[34816];  // 16KB A + 16KB B (+epilogue tile)

  int tid = threadIdx.x, wid = tid >> 6, lane = tid & 63;
  int q = lane >> 4, l16 = lane & 15;
  int wm = wid >> 1, wn = wid & 1;

  const __bf16* gp[8];
  uint32_t lo[8];
#pragma unroll
  for (int u = 0; u < 8; ++u) {
    int c = wid * 8 + u;
    int isB = c >> 4;
    int blk = (c & 15) >> 1;
    int ks = c & 1;
    const __bf16* base = isB ? Bbp : Ab;
    gp[u] = base + (size_t)(blk * 16 + l16) * K + ks * 32 + q * 8;
    lo[u] = (uint32_t)(isB * 16384 + (blk * 2 + ks) * 1024);
  }

  f32x4 acc[4][4];
  f32x4 zero = {0.f, 0.f, 0.f, 0.f};
#pragma unroll
  for (int i = 0; i < 4; ++i)
#pragma unroll
    for (int j = 0; j < 4; ++j) acc[i][j] = zero;

  for (int kt = 0; kt < K / 64; ++kt) {
    __syncthreads();
#pragma unroll
    for (int u = 0; u < 8; ++u) load_lds16(gp[u], smem + lo[u]);
    __syncthreads();
#pragma unroll
    for (int ks = 0; ks < 2; ++ks) {
      bf16x8 a[4], bb[4];
#pragma unroll
      for (int i = 0; i < 4; ++i)
        a[i] = *(const bf16x8*)(smem + (((wm * 4 + i) * 2 + ks) * 64 + lane) * 16);
#pragma unroll
      for (int j = 0; j < 4; ++j)
        bb[j] = *(const bf16x8*)(smem + 16384 + (((wn * 4 + j) * 2 + ks) * 64 + lane) * 16);
#pragma unroll
      for (int i = 0; i < 4; ++i)
#pragma unroll
        for (int j = 0; j < 4; ++j)
          acc[i][j] = __builtin_amdgcn_mfma_f32_16x16x32_bf16(a[i], bb[j], acc[i][j], 0, 0, 0);
    }
#pragma unroll
    for (int u = 0; u < 8; ++u) gp[u] += 64;
  }

  float bias[4];
#pragma unroll
  for (int j = 0; j < 4; ++j) bias[j] = b1p[nt * 128 + wn * 64 + j * 16 + l16];

  __syncthreads();
  __bf16* tile = (__bf16*)smem;  // [128][136]
#pragma unroll
  for (int i = 0; i < 4; ++i)
#pragma unroll
    for (int j = 0; j < 4; ++j)
#pragma unroll
      for (int r2 = 0; r2 < 4; ++r2) {
        float x = acc[i][j][r2] + bias[j];
        int row = wm * 64 + i * 16 + q * 4 + r2;
        int col = wn * 64 + j * 16 + l16;
        tile[row * 136 + col] = (__bf16)(wgt * gelu_tanh(x));
      }
  __syncthreads();
  __bf16* Hrow = Hbuf + ((size_t)(bl * 3 + s) * Ll + mt * 128) * Hh + nt * 128;
#pragma unroll
  for (int t2 = 0; t2 < 8; ++t2) {
    int gidx = t2 * 256 + tid;
    int row = gidx >> 4, cg = gidx & 15;
    bf16x8 v = *(const bf16x8*)(tile + row * 136 + cg * 8);
    *(bf16x8*)(Hrow + (size_t)row * Hh + cg * 8) = v;
  }
}

// ---- GEMM2: per-slot single-buf K-loop; KC template; XCD swizzle ----
// lid = nt + 8*(mt + 3*(kc + NKC*bl)), chunk = one bl per XCD.

template <int KC>
__global__ __launch_bounds__(256, 4) void gemm2_kernel(
    const __bf16* __restrict__ Hbuf, const __bf16* __restrict__ W2T,
    const __bf16* __restrict__ S2T, const float* __restrict__ eb2,
    const float* __restrict__ sb2, const int* __restrict__ slotE,
    const float* __restrict__ slotW, float* __restrict__ out,
    __bf16* __restrict__ pbuf, int bbase, int bc) {
  constexpr int K = Hh;          // 4096 total
  constexpr int NKC = Hh / KC;   // K chunks (4 or 8)
  int bid = blockIdx.x, nwg = gridDim.x;
  int lid = (bid & 7) * (nwg >> 3) + (bid >> 3);  // XCD-chunked (nwg % 8 == 0)
  int nt = lid & 7;
  int r = lid >> 3;
  int mt = r % 3; r /= 3;
  int kc = r % NKC;
  int bl = r / NKC;
  int b = bbase + bl;

  __shared__ __align__(16) char smem[34816];

  int tid = threadIdx.x, wid = tid >> 6, lane = tid & 63;
  int q = lane >> 4, l16 = lane & 15;
  int wm = wid >> 1, wn = wid & 1;

  f32x4 acc[4][4];
  f32x4 zero = {0.f, 0.f, 0.f, 0.f};
#pragma unroll
  for (int i = 0; i < 4; ++i)
#pragma unroll
    for (int j = 0; j < 4; ++j) acc[i][j] = zero;
  float biasacc[4] = {0.f, 0.f, 0.f, 0.f};

  for (int s = 0; s < 3; ++s) {
    int e = (s == 2) ? Ee : slotE[b * 4 + s];
    if ((e == 1 && mt == 1) || (e == 2 && mt == 0)) continue;  // masked slot
    float wgt = (s == 2) ? 1.0f : slotW[b * 4 + s];

    const __bf16* Ab = Hbuf + ((size_t)(bl * 3 + s) * Ll + mt * 128) * K + (size_t)kc * KC;
    const __bf16* Bbp = (e < Ee ? W2T + (size_t)e * Dd * K : S2T) + (size_t)(nt * 128) * K + (size_t)kc * KC;

    const __bf16* gp[8];
    uint32_t lo[8];
#pragma unroll
    for (int u = 0; u < 8; ++u) {
      int c = wid * 8 + u;
      int isB = c >> 4;
      int blk = (c & 15) >> 1;
      int ks = c & 1;
      const __bf16* base = isB ? Bbp : Ab;
      gp[u] = base + (size_t)(blk * 16 + l16) * K + ks * 32 + q * 8;
      lo[u] = (uint32_t)(isB * 16384 + (blk * 2 + ks) * 1024);
    }

    for (int kt = 0; kt < KC / 64; ++kt) {
      __syncthreads();
#pragma unroll
      for (int u = 0; u < 8; ++u) load_lds16(gp[u], smem + lo[u]);
      __syncthreads();
#pragma unroll
      for (int ks = 0; ks < 2; ++ks) {
        bf16x8 a[4], bb[4];
#pragma unroll
        for (int i = 0; i < 4; ++i)
          a[i] = *(const bf16x8*)(smem + (((wm * 4 + i) * 2 + ks) * 64 + lane) * 16);
#pragma unroll
        for (int j = 0; j < 4; ++j)
          bb[j] = *(const bf16x8*)(smem + 16384 + (((wn * 4 + j) * 2 + ks) * 64 + lane) * 16);
#pragma unroll
        for (int i = 0; i < 4; ++i)
#pragma unroll
          for (int j = 0; j < 4; ++j)
            acc[i][j] = __builtin_amdgcn_mfma_f32_16x16x32_bf16(a[i], bb[j], acc[i][j], 0, 0, 0);
      }
#pragma unroll
      for (int u = 0; u < 8; ++u) gp[u] += 64;
    }

    if (kc == 0) {
      const float* b2p = (e < Ee ? eb2 + e * Dd : sb2);
#pragma unroll
      for (int j = 0; j < 4; ++j)
        biasacc[j] += wgt * b2p[nt * 128 + wn * 64 + j * 16 + l16];
    }
  }

  if (pbuf) {
    // non-atomic bf16 partial store via LDS repack (coalesced bf16x8)
    __syncthreads();
    __bf16* tile = (__bf16*)smem;  // [128][136]
#pragma unroll
    for (int i = 0; i < 4; ++i)
#pragma unroll
      for (int j = 0; j < 4; ++j)
#pragma unroll
        for (int r2 = 0; r2 < 4; ++r2) {
          int row = wm * 64 + i * 16 + q * 4 + r2;
          int col = wn * 64 + j * 16 + l16;
          tile[row * 136 + col] = (__bf16)(acc[i][j][r2] + biasacc[j]);
        }
    __syncthreads();
    __bf16* Prow = pbuf + (((size_t)(kc * bc + bl) * Ll + mt * 128)) * Dd + nt * 128;
#pragma unroll
    for (int t2 = 0; t2 < 8; ++t2) {
      int gidx = t2 * 256 + tid;
      int row = gidx >> 4, cg = gidx & 15;
      bf16x8 v = *(const bf16x8*)(tile + row * 136 + cg * 8);
      *(bf16x8*)(Prow + (size_t)row * Dd + cg * 8) = v;
    }
  } else {
    float* orow = out + ((size_t)(b * Ll + mt * 128)) * Dd + nt * 128;
#pragma unroll
    for (int i = 0; i < 4; ++i)
#pragma unroll
      for (int j = 0; j < 4; ++j)
#pragma unroll
        for (int r2 = 0; r2 < 4; ++r2) {
          int row = wm * 64 + i * 16 + q * 4 + r2;
          int col = wn * 64 + j * 16 + l16;
          atomicAdd(orow + (size_t)row * Dd + col, acc[i][j][r2] + biasacc[j]);
        }
  }
}

// reduce: out[i] = sum_{kc<nkc} pbuf[kc][i]  (8 elems/thread)
__global__ void reduce_kernel(const __bf16* __restrict__ pbuf, float* __restrict__ out,
                              int n8, size_t stride, int nkc) {
  int i = blockIdx.x * blockDim.x + threadIdx.x;
  if (i >= n8) return;
  size_t base = (size_t)i * 8;
  float sum[8];
#pragma unroll
  for (int k = 0; k < 8; ++k) sum[k] = 0.f;
  for (int kc = 0; kc < nkc; ++kc) {
    bf16x8 v = *(const bf16x8*)(pbuf + kc * stride + base);
#pragma unroll
    for (int k = 0; k < 8; ++k) sum[k] += (float)v[k];
  }
  float4 o0 = {sum[0], sum[1], sum[2], sum[3]};
  float4 o1 = {sum[4], sum[5], sum[6], sum[7]};
  *(float4*)(out + base) = o0;
  *(float4*)(out + base + 4) = o1;
}

// ---------------- host ----------------

extern "C" void kernel_launch(void* const* d_in, const int* in_sizes, int n_in,
                              void* d_out, int out_size, void* d_ws, size_t ws_size,
                              hipStream_t stream) {
  (void)in_sizes; (void)n_in;
  const float* ctx = (const float*)d_in[0];
  const float* tc  = (const float*)d_in[1];
  const float* gW  = (const float*)d_in[2];
  const float* gb  = (const float*)d_in[3];
  const float* tW  = (const float*)d_in[4];
  const float* tb  = (const float*)d_in[5];
  const float* eW1 = (const float*)d_in[6];
  const float* eb1 = (const float*)d_in[7];
  const float* eW2 = (const float*)d_in[8];
  const float* eb2 = (const float*)d_in[9];
  const float* sW1 = (const float*)d_in[10];
  const float* sb1 = (const float*)d_in[11];
  const float* sW2 = (const float*)d_in[12];
  const float* sb2 = (const float*)d_in[13];
  float* out = (float*)d_out;

  char* ws = (char*)d_ws;
  size_t off = 0;
  auto alloc = [&](size_t sz) { size_t o = off; off += (sz + 255) & ~(size_t)255; return o; };
  size_t oW1T = alloc((size_t)Ee * Hh * Dd * 2);
  size_t oW2T = alloc((size_t)Ee * Dd * Hh * 2);
  size_t oS1T = alloc((size_t)Hh * Dd * 2);
  size_t oS2T = alloc((size_t)Dd * Hh * 2);
  size_t oX   = alloc((size_t)Bb * Ll * Dd * 2);
  size_t oP   = alloc((size_t)Bb * 6 * Dd * 4);
  size_t oSE  = alloc(Bb * 4 * sizeof(int));
  size_t oSW  = alloc(Bb * 4 * sizeof(float));
  size_t fixed = off;

  // plan selection: bc = batches/chunk, nkc = gemm2 K-split, use_pbuf = non-atomic
  auto hbufB = [&](int bc) { return (size_t)bc * 3 * Ll * Hh * 2; };
  auto pbufB = [&](int bc, int nkc) { return (size_t)nkc * bc * Ll * Dd * 2; };
  int bc = 1; bool use_pbuf = false; int nkc = 4;
  if (fixed + hbufB(8) + pbufB(8, 8) + 512 <= ws_size)      { bc = 8; use_pbuf = true; nkc = 8; }
  else if (fixed + hbufB(8) + pbufB(8, 4) + 512 <= ws_size) { bc = 8; use_pbuf = true; nkc = 4; }
  else if (fixed + hbufB(4) + pbufB(4, 4) + 512 <= ws_size) { bc = 4; use_pbuf = true; nkc = 4; }
  else if (fixed + hbufB(4) + 512 <= ws_size)               { bc = 4; use_pbuf = false; nkc = 4; }
  else if (fixed + hbufB(2) + 512 <= ws_size)               { bc = 2; use_pbuf = false; nkc = 4; }
  else                                                      { bc = 1; use_pbuf = false; nkc = 4; }
  int nchunk = Bb / bc;
  size_t oH = alloc(hbufB(bc));
  size_t oPB = use_pbuf ? alloc(pbufB(bc, nkc)) : 0;

  __bf16* W1T = (__bf16*)(ws + oW1T);
  __bf16* W2T = (__bf16*)(ws + oW2T);
  __bf16* S1T = (__bf16*)(ws + oS1T);
  __bf16* S2T = (__bf16*)(ws + oS2T);
  __bf16* Xbf = (__bf16*)(ws + oX);
  float*  part = (float*)(ws + oP);
  int*    slotE = (int*)(ws + oSE);
  float*  slotW = (float*)(ws + oSW);
  __bf16* Hbuf = (__bf16*)(ws + oH);
  __bf16* Pbuf = use_pbuf ? (__bf16*)(ws + oPB) : nullptr;

  // pbuf path fully overwrites out via reduce -> memset only needed for atomics
  if (!use_pbuf)
    hipMemsetAsync(d_out, 0, (size_t)out_size * sizeof(float), stream);

  cvt_x_kernel<<<(Bb * Ll * Dd / 4 + 255) / 256, 256, 0, stream>>>(ctx, Xbf, Bb * Ll * Dd / 4);
  transpose_cvt_kernel<<<dim3(Hh / 32, Dd / 32, Ee), 256, 0, stream>>>(eW1, W1T, Dd, Hh);
  transpose_cvt_kernel<<<dim3(Dd / 32, Hh / 32, Ee), 256, 0, stream>>>(eW2, W2T, Hh, Dd);
  transpose_cvt_kernel<<<dim3(Hh / 32, Dd / 32, 1), 256, 0, stream>>>(sW1, S1T, Dd, Hh);
  transpose_cvt_kernel<<<dim3(Dd / 32, Hh / 32, 1), 256, 0, stream>>>(sW2, S2T, Hh, Dd);
  agg_kernel<<<dim3(6, Bb), 256, 0, stream>>>(ctx, part);
  gate_kernel<<<Bb, 256, 0, stream>>>(part, tc, gW, gb, tW, tb, slotE, slotW);

  for (int c = 0; c < nchunk; ++c) {
    // gemm1: 1-D grid, 288 blocks per batch (32 nt x 3 mt x 3 s), %8==0
    gemm1_kernel<<<dim3(288 * bc), 256, 0, stream>>>(
        Xbf, W1T, S1T, eb1, sb1, slotE, slotW, Hbuf, c * bc);
    // gemm2: 1-D grid, 8 nt x 3 mt x nkc x bc, %8==0
    int g2 = 8 * 3 * nkc * bc;
    if (nkc == 8)
      gemm2_kernel<512><<<dim3(g2), 256, 0, stream>>>(
          Hbuf, W2T, S2T, eb2, sb2, slotE, slotW, out, Pbuf, c * bc, bc);
    else
      gemm2_kernel<1024><<<dim3(g2), 256, 0, stream>>>(
          Hbuf, W2T, S2T, eb2, sb2, slotE, slotW, out, Pbuf, c * bc, bc);
    if (use_pbuf) {
      int n8 = bc * Ll * Dd / 8;
      reduce_kernel<<<(n8 + 255) / 256, 256, 0, stream>>>(
          Pbuf, out + (size_t)c * bc * Ll * Dd, n8, (size_t)bc * Ll * Dd, nkc);
    }
  }
}